// Round 11
// baseline (210.896 us; speedup 1.0000x reference)
//
#include <hip/hip_runtime.h>
#include <stdint.h>

#define DEVINL __device__ __forceinline__

typedef __bf16 bf16x8 __attribute__((ext_vector_type(8)));
typedef float f32x4 __attribute__((ext_vector_type(4)));
typedef float f32x16 __attribute__((ext_vector_type(16)));
typedef uint32_t u32x4 __attribute__((ext_vector_type(4)));

DEVINL uint16_t f2bf(float f) {
    uint32_t u = __builtin_bit_cast(uint32_t, f);
    uint32_t r = (u + 0x7FFFu + ((u >> 16) & 1u)) >> 16;
    return (uint16_t)r;
}

DEVINL bf16x8 ld8(const uint16_t* p) {
    u32x4 v = *(const u32x4*)p;
    return __builtin_bit_cast(bf16x8, v);
}

DEVINL void gload16(const void* g, void* l) {
    __builtin_amdgcn_global_load_lds(
        (const __attribute__((address_space(1))) uint32_t*)g,
        (__attribute__((address_space(3))) uint32_t*)l, 16, 0, 0);
}

DEVINL uint32_t cvtpk(float lo, float hi) {
    uint32_t r;
    asm("v_cvt_pk_bf16_f32 %0, %1, %2" : "=v"(r) : "v"(lo), "v"(hi));
    return r;
}

DEVINL float exp2_fast(float x) {
    float r;
    asm("v_exp_f32 %0, %1" : "=v"(r) : "v"(x));
    return r;
}

// ---------------- fused prep: cvt x -> bf16 ; transpose+cvt Wqkv, Wproj ----------------
DEVINL void transW_body(const float* __restrict__ W, uint16_t* __restrict__ WT,
                        int Nn, int n0, int k0, int tid, uint16_t* t) {
#pragma unroll
    for (int i = 0; i < 4; ++i) {
        int c = tid + i * 256;              // 1024 float4 chunks
        int kr = c >> 4, nc = c & 15;
        float4 v = *(const float4*)(W + (size_t)(k0 + kr) * Nn + n0 + nc * 4);
        t[(nc * 4 + 0) * 65 + kr] = f2bf(v.x);
        t[(nc * 4 + 1) * 65 + kr] = f2bf(v.y);
        t[(nc * 4 + 2) * 65 + kr] = f2bf(v.z);
        t[(nc * 4 + 3) * 65 + kr] = f2bf(v.w);
    }
    __syncthreads();
#pragma unroll
    for (int i = 0; i < 2; ++i) {
        int c = tid + i * 256;              // 512 chunks of 8 bf16
        int nr = c >> 3, kc = c & 7;
        union { uint16_t u[8]; u32x4 v; } o;
#pragma unroll
        for (int j = 0; j < 8; ++j) o.u[j] = t[nr * 65 + kc * 8 + j];
        *(u32x4*)(WT + (size_t)(n0 + nr) * 1024 + k0 + kc * 8) = o.v;
    }
}

__global__ void k_prep(const float* __restrict__ x, uint16_t* __restrict__ xb,
                       const float* __restrict__ Wqkv, uint16_t* __restrict__ wqkvT,
                       const float* __restrict__ Wproj, uint16_t* __restrict__ wprojT) {
    __shared__ uint16_t t[64 * 65];
    int bid = blockIdx.x;
    int tid = threadIdx.x;
    if (bid < 4096) {
        int i = bid * 256 + tid;            // 1048576 chunks of 8 floats
        const float4* src = (const float4*)x + (size_t)i * 2;
        float4 a = src[0], b = src[1];
        union { uint16_t u[8]; u32x4 v; } o;
        o.u[0] = f2bf(a.x); o.u[1] = f2bf(a.y); o.u[2] = f2bf(a.z); o.u[3] = f2bf(a.w);
        o.u[4] = f2bf(b.x); o.u[5] = f2bf(b.y); o.u[6] = f2bf(b.z); o.u[7] = f2bf(b.w);
        ((u32x4*)xb)[i] = o.v;
    } else if (bid < 4864) {
        int idx = bid - 4096;               // 48 x 16 tiles
        transW_body(Wqkv, wqkvT, 3072, (idx % 48) * 64, (idx / 48) * 64, tid, t);
    } else {
        int idx = bid - 4864;               // 16 x 16 tiles
        transW_body(Wproj, wprojT, 1024, (idx % 16) * 64, (idx / 16) * 64, tid, t);
    }
}

// ---------------- GEMM: [8192][1024] x BT[Nd][1024] ----------------
// XCD-panel-blocked 1D grid: xcd = bid&7 owns M-tiles [xcd*8, xcd*8+8);
// within an XCD blocks walk B-panel-major.
// MODE 0: QKV -> q(*0.125*log2e)/k scattered as [bh][n][64];
//   v-blocks (nt>=16) transpose their 128x128 acc tile in LDS and store
//   v^T [bh][dh][n] as contiguous 256B runs (R6 lesson: direct scatter = 1
//   line per lane; this path is coalesced).
// MODE 1: proj -> out f32 [8192][1024] + bias
template <int MODE>
__global__ __launch_bounds__(256) void k_gemm(
    const uint16_t* __restrict__ A, const uint16_t* __restrict__ BT,
    const float* __restrict__ bias,
    uint16_t* __restrict__ qo, uint16_t* __restrict__ ko, uint16_t* __restrict__ vo,
    float* __restrict__ out) {
    __shared__ uint16_t smem[16640];        // a_lds[8192] + b_lds[8192]; v-epilogue reuses as [128][130]
    uint16_t* a_lds = smem;
    uint16_t* b_lds = smem + 8192;
    int tid = threadIdx.x;
    int w = tid >> 6, l = tid & 63;
    int l15 = l & 15, l4 = l >> 4;
    int bid = blockIdx.x;
    int mt = ((bid & 7) << 3) + ((bid >> 3) & 7);   // xcd*8 + local M index
    int nt = bid >> 6;                               // B-panel index
    int m0 = mt * 128, n0 = nt * 128;
    int wr = w >> 1, wc = w & 1;
    f32x4 acc[4][4] = {};

    for (int kt = 0; kt < 16; ++kt) {
#pragma unroll
        for (int i = 0; i < 4; ++i) {
            int c = i * 256 + w * 64 + l;
            int row = c >> 3, slot = c & 7;
            int kc = slot ^ (row & 7);
            gload16(A + (size_t)(m0 + row) * 1024 + kt * 64 + kc * 8,
                    a_lds + (size_t)(i * 256 + w * 64) * 8);
            gload16(BT + (size_t)(n0 + row) * 1024 + kt * 64 + kc * 8,
                    b_lds + (size_t)(i * 256 + w * 64) * 8);
        }
        __syncthreads();
#pragma unroll
        for (int kkk = 0; kkk < 2; ++kkk) {
            bf16x8 af[4], bfr[4];
#pragma unroll
            for (int i = 0; i < 4; ++i) {
                int row = wr * 64 + i * 16 + l15;
                af[i] = ld8(a_lds + row * 64 + ((kkk * 4 + l4) ^ (row & 7)) * 8);
                int rowb = wc * 64 + i * 16 + l15;
                bfr[i] = ld8(b_lds + rowb * 64 + ((kkk * 4 + l4) ^ (rowb & 7)) * 8);
            }
#pragma unroll
            for (int i = 0; i < 4; ++i)
#pragma unroll
                for (int j = 0; j < 4; ++j)
                    acc[i][j] = __builtin_amdgcn_mfma_f32_16x16x32_bf16(
                        af[i], bfr[j], acc[i][j], 0, 0, 0);
        }
        __syncthreads();
    }

    if constexpr (MODE == 0) {
        if (n0 >= 2048) {
            // ---- v-block: transpose 128x128 acc tile in LDS, store v^T coalesced ----
            // smem as [128 d][130] (row stride 130 words -> bank stride 2, light conflicts)
#pragma unroll
            for (int i = 0; i < 4; ++i)
#pragma unroll
                for (int j = 0; j < 4; ++j) {
                    int dl = wc * 64 + j * 16 + l15;
                    int ml = wr * 64 + i * 16 + l4 * 4;
                    union { uint16_t u[4]; uint2 v2; } pk;
#pragma unroll
                    for (int r = 0; r < 4; ++r) pk.u[r] = f2bf(acc[i][j][r]);
                    *(uint2*)&smem[dl * 130 + ml] = pk.v2;
                }
            __syncthreads();
            int b = m0 >> 11, nbase = m0 & 2047;
#pragma unroll
            for (int pass = 0; pass < 8; ++pass) {
                int dl = pass * 16 + (tid >> 4);          // 0..127
                int mloc = (tid & 15) * 8;                // 0..120
                u32x4 val = *(u32x4*)&smem[dl * 130 + mloc];
                int d = n0 + dl;                          // 2048..3071
                int h = (d >> 6) & 15, dh = d & 63;
                *(u32x4*)(vo + ((size_t)(b * 16 + h) * 64 + dh) * 2048 + nbase + mloc) = val;
            }
        } else {
#pragma unroll
            for (int i = 0; i < 4; ++i)
#pragma unroll
                for (int j = 0; j < 4; ++j) {
                    int d = n0 + wc * 64 + j * 16 + l15;
                    int s = d >> 10, h = (d >> 6) & 15, dh = d & 63;
                    uint16_t* dst0 = (s == 0) ? qo : ko;
                    // q pre-scaled by Dh^-0.5 * log2(e) so softmax runs in exp2 domain
                    float sc = (s == 0) ? 0.18033688011112042f : 1.0f;
#pragma unroll
                    for (int r = 0; r < 4; ++r) {
                        int m = m0 + wr * 64 + i * 16 + l4 * 4 + r;
                        int b = m >> 11, n = m & 2047;
                        dst0[((size_t)(b * 16 + h) * 2048 + n) * 64 + dh] = f2bf(acc[i][j][r] * sc);
                    }
                }
        }
    } else {
#pragma unroll
        for (int j = 0; j < 4; ++j) {
            int d = n0 + wc * 64 + j * 16 + l15;
            float bv = bias[d];
#pragma unroll
            for (int i = 0; i < 4; ++i)
#pragma unroll
                for (int r = 0; r < 4; ++r) {
                    int m = m0 + wr * 64 + i * 16 + l4 * 4 + r;
                    out[(size_t)m * 1024 + d] = acc[i][j][r] + bv;
                }
        }
    }
}

// ---------------- flash attention (no-max softmax, exp2 domain) ----------------
// R7-proven body: split-barrier counted-vmcnt pipeline, K/V in LDS, scalar
// lsum, XCD swizzle. R11 micro: QK accumulation split into two independent
// 2-chains (sA/sB) to halve MFMA dependency latency.
__global__ __launch_bounds__(256) void k_attn(
    const uint16_t* __restrict__ q, const uint16_t* __restrict__ kk_,
    const uint16_t* __restrict__ vt, uint16_t* __restrict__ o) {
    __shared__ uint16_t k_lds[2][64 * 64];
    __shared__ uint16_t v_lds[2][64 * 64];
    int tid = threadIdx.x;
    int w = tid >> 6, l = tid & 63;
    int l31 = l & 31, g = l >> 5;
    int bid = blockIdx.x;
    int slot = bid >> 3;
    int bh = (bid & 7) * 8 + (slot >> 4);
    int qt = slot & 15;
    int qrow = qt * 128 + w * 32 + l31;
    const uint16_t* qb = q + ((size_t)bh * 2048 + qrow) * 64;
    const uint16_t* kbase = kk_ + (size_t)bh * 2048 * 64;
    const uint16_t* vbase = vt + (size_t)bh * 64 * 2048;

    bf16x8 qf[4];
#pragma unroll
    for (int kv = 0; kv < 4; ++kv) qf[kv] = ld8(qb + kv * 16 + g * 8);

    // staging source pointers (lane-fixed, advanced by constants each tile)
    int c0 = w * 128 + l;
    int rr0 = c0 >> 3, sl0 = c0 & 7;
    int kc0 = sl0 ^ (rr0 & 7);
    int rr1 = rr0 + 8, kc1 = sl0 ^ (rr1 & 7);
    const uint16_t* kp0 = kbase + rr0 * 64 + kc0 * 8;
    const uint16_t* kp1 = kbase + rr1 * 64 + kc1 * 8;
    const uint16_t* vp0 = vbase + (size_t)rr0 * 2048 + kc0 * 8;
    const uint16_t* vp1 = vbase + (size_t)rr1 * 2048 + kc1 * 8;
    uint16_t* kd0 = k_lds[0] + w * 1024;
    uint16_t* kd1 = k_lds[1] + w * 1024;
    uint16_t* vd0 = v_lds[0] + w * 1024;
    uint16_t* vd1 = v_lds[1] + w * 1024;

    f32x16 oa[2] = {};
    float lsum = 0.f;

    auto stage = [&](uint16_t* kd, uint16_t* vd) {
        gload16(kp0, kd);       gload16(kp1, kd + 512);   // K first,
        gload16(vp0, vd);       gload16(vp1, vd + 512);   // V second (vmcnt order)
        kp0 += 4096; kp1 += 4096; vp0 += 64; vp1 += 64;
    };

    stage(kd0, vd0);   // tile 0 -> buf 0  (4 outstanding)

    auto body = [&](int t, const uint16_t* kb, const uint16_t* vb,
                    uint16_t* kdn, uint16_t* vdn) {
        // K(t) ready for all waves
        asm volatile("s_waitcnt vmcnt(2)\n\ts_barrier" ::: "memory");
        if (t < 31) stage(kdn, vdn);   // issue next tile ASAP (lands during compute)

        // S^T = K * Q^T, then P = exp2(S) in-register (32 keys at a time)
        bf16x8 pfrag[4];
#pragma unroll
        for (int j = 0; j < 2; ++j) {
            int key = j * 32 + l31;
            f32x16 sA = {}, sB = {};
            __builtin_amdgcn_s_setprio(1);
            {
                bf16x8 kf0 = ld8(kb + key * 64 + ((0 + g) ^ (key & 7)) * 8);
                bf16x8 kf1 = ld8(kb + key * 64 + ((2 + g) ^ (key & 7)) * 8);
                bf16x8 kf2 = ld8(kb + key * 64 + ((4 + g) ^ (key & 7)) * 8);
                bf16x8 kf3 = ld8(kb + key * 64 + ((6 + g) ^ (key & 7)) * 8);
                sA = __builtin_amdgcn_mfma_f32_32x32x16_bf16(kf0, qf[0], sA, 0, 0, 0);
                sB = __builtin_amdgcn_mfma_f32_32x32x16_bf16(kf1, qf[1], sB, 0, 0, 0);
                sA = __builtin_amdgcn_mfma_f32_32x32x16_bf16(kf2, qf[2], sA, 0, 0, 0);
                sB = __builtin_amdgcn_mfma_f32_32x32x16_bf16(kf3, qf[3], sB, 0, 0, 0);
            }
            __builtin_amdgcn_s_setprio(0);
            f32x16 stj = sA + sB;
#pragma unroll
            for (int h = 0; h < 2; ++h) {
                float e[8];
#pragma unroll
                for (int jj = 0; jj < 8; ++jj) e[jj] = exp2_fast(stj[h * 8 + jj]);
                lsum += ((e[0] + e[1]) + (e[2] + e[3])) + ((e[4] + e[5]) + (e[6] + e[7]));
                uint32_t a0 = cvtpk(e[0], e[1]), a1 = cvtpk(e[2], e[3]);
                uint32_t b0 = cvtpk(e[4], e[5]), b1 = cvtpk(e[6], e[7]);
                auto r0 = __builtin_amdgcn_permlane32_swap(a0, b0, false, false);
                auto r1 = __builtin_amdgcn_permlane32_swap(a1, b1, false, false);
                u32x4 f;
                f[0] = r0[0]; f[1] = r1[0]; f[2] = r0[1]; f[3] = r1[1];
                pfrag[j * 2 + h] = __builtin_bit_cast(bf16x8, f);
            }
        }

        // V(t) ready for all waves
        if (t < 31) asm volatile("s_waitcnt vmcnt(4)\n\ts_barrier" ::: "memory");
        else        asm volatile("s_waitcnt vmcnt(0)\n\ts_barrier" ::: "memory");

        // O^T += V^T * P^T
        __builtin_amdgcn_s_setprio(1);
#pragma unroll
        for (int kv = 0; kv < 4; ++kv) {
#pragma unroll
            for (int dt = 0; dt < 2; ++dt) {
                int dh = dt * 32 + l31;
                bf16x8 vf = ld8(vb + dh * 64 + ((2 * kv + g) ^ (dh & 7)) * 8);
                oa[dt] = __builtin_amdgcn_mfma_f32_32x32x16_bf16(vf, pfrag[kv], oa[dt], 0, 0, 0);
            }
        }
        __builtin_amdgcn_s_setprio(0);
    };

    for (int kt = 0; kt < 32; kt += 2) {
        body(kt,     k_lds[0], v_lds[0], kd1, vd1);
        body(kt + 1, k_lds[1], v_lds[1], kd0, vd0);
    }

    float ltot = lsum + __shfl_xor(lsum, 32, 64);
    float inv = 1.0f / ltot;
    int b = bh >> 4, h = bh & 15;
    uint16_t* ob = o + ((size_t)(b * 2048 + qrow)) * 1024 + h * 64;
#pragma unroll
    for (int dt = 0; dt < 2; ++dt)
#pragma unroll
        for (int rq = 0; rq < 4; ++rq) {
            union { uint16_t u[4]; uint2 v; } pk;
#pragma unroll
            for (int rr = 0; rr < 4; ++rr) pk.u[rr] = f2bf(oa[dt][rq * 4 + rr] * inv);
            int dh0 = dt * 32 + rq * 8 + g * 4;
            *(uint2*)(ob + dh0) = pk.v;
        }
}

extern "C" void kernel_launch(void* const* d_in, const int* in_sizes, int n_in,
                              void* d_out, int out_size, void* d_ws, size_t ws_size,
                              hipStream_t stream) {
    const float* x     = (const float*)d_in[0];
    // d_in[1] = xpos : unused by the reference
    const float* Wqkv  = (const float*)d_in[2];
    const float* Wproj = (const float*)d_in[3];
    const float* bproj = (const float*)d_in[4];
    float* out = (float*)d_out;

    char* ws = (char*)d_ws;
    uint16_t* xb     = (uint16_t*)(ws);                         // 16.78 MB
    uint16_t* wqkvT  = (uint16_t*)(ws + 16777216);              //  6.29 MB
    uint16_t* wprojT = (uint16_t*)(ws + 23068672);              //  2.10 MB
    uint16_t* qws    = (uint16_t*)(ws + 25165824);              // 16.78 MB
    uint16_t* kws    = (uint16_t*)(ws + 41943040);              // 16.78 MB
    uint16_t* vT     = (uint16_t*)(ws + 58720256);              // 16.78 MB (total ~75.5 MB)
    uint16_t* attnout = xb;  // xb is dead after QKV GEMM

    k_prep<<<dim3(5120), dim3(256), 0, stream>>>(x, xb, Wqkv, wqkvT, Wproj, wprojT);
    k_gemm<0><<<dim3(1536), dim3(256), 0, stream>>>(xb, wqkvT, nullptr, qws, kws, vT, nullptr);
    k_attn<<<dim3(1024), dim3(256), 0, stream>>>(qws, kws, vT, attnout);
    k_gemm<1><<<dim3(512), dim3(256), 0, stream>>>(attnout, wprojT, bproj, nullptr, nullptr, nullptr, out);
}

// Round 12
// 204.381 us; speedup vs baseline: 1.0319x; 1.0319x over previous
//
#include <hip/hip_runtime.h>
#include <stdint.h>

#define DEVINL __device__ __forceinline__

typedef __bf16 bf16x8 __attribute__((ext_vector_type(8)));
typedef float f32x4 __attribute__((ext_vector_type(4)));
typedef float f32x16 __attribute__((ext_vector_type(16)));
typedef uint32_t u32x4 __attribute__((ext_vector_type(4)));

DEVINL uint16_t f2bf(float f) {
    uint32_t u = __builtin_bit_cast(uint32_t, f);
    uint32_t r = (u + 0x7FFFu + ((u >> 16) & 1u)) >> 16;
    return (uint16_t)r;
}

DEVINL bf16x8 ld8(const uint16_t* p) {
    u32x4 v = *(const u32x4*)p;
    return __builtin_bit_cast(bf16x8, v);
}

DEVINL void gload16(const void* g, void* l) {
    __builtin_amdgcn_global_load_lds(
        (const __attribute__((address_space(1))) uint32_t*)g,
        (__attribute__((address_space(3))) uint32_t*)l, 16, 0, 0);
}

DEVINL uint32_t cvtpk(float lo, float hi) {
    uint32_t r;
    asm("v_cvt_pk_bf16_f32 %0, %1, %2" : "=v"(r) : "v"(lo), "v"(hi));
    return r;
}

DEVINL float exp2_fast(float x) {
    float r;
    asm("v_exp_f32 %0, %1" : "=v"(r) : "v"(x));
    return r;
}

// ---------------- fused prep: cvt x -> bf16 ; transpose+cvt Wqkv, Wproj ----------------
DEVINL void transW_body(const float* __restrict__ W, uint16_t* __restrict__ WT,
                        int Nn, int n0, int k0, int tid, uint16_t* t) {
#pragma unroll
    for (int i = 0; i < 4; ++i) {
        int c = tid + i * 256;              // 1024 float4 chunks
        int kr = c >> 4, nc = c & 15;
        float4 v = *(const float4*)(W + (size_t)(k0 + kr) * Nn + n0 + nc * 4);
        t[(nc * 4 + 0) * 65 + kr] = f2bf(v.x);
        t[(nc * 4 + 1) * 65 + kr] = f2bf(v.y);
        t[(nc * 4 + 2) * 65 + kr] = f2bf(v.z);
        t[(nc * 4 + 3) * 65 + kr] = f2bf(v.w);
    }
    __syncthreads();
#pragma unroll
    for (int i = 0; i < 2; ++i) {
        int c = tid + i * 256;              // 512 chunks of 8 bf16
        int nr = c >> 3, kc = c & 7;
        union { uint16_t u[8]; u32x4 v; } o;
#pragma unroll
        for (int j = 0; j < 8; ++j) o.u[j] = t[nr * 65 + kc * 8 + j];
        *(u32x4*)(WT + (size_t)(n0 + nr) * 1024 + k0 + kc * 8) = o.v;
    }
}

__global__ void k_prep(const float* __restrict__ x, uint16_t* __restrict__ xb,
                       const float* __restrict__ Wqkv, uint16_t* __restrict__ wqkvT,
                       const float* __restrict__ Wproj, uint16_t* __restrict__ wprojT) {
    __shared__ uint16_t t[64 * 65];
    int bid = blockIdx.x;
    int tid = threadIdx.x;
    if (bid < 4096) {
        int i = bid * 256 + tid;            // 1048576 chunks of 8 floats
        const float4* src = (const float4*)x + (size_t)i * 2;
        float4 a = src[0], b = src[1];
        union { uint16_t u[8]; u32x4 v; } o;
        o.u[0] = f2bf(a.x); o.u[1] = f2bf(a.y); o.u[2] = f2bf(a.z); o.u[3] = f2bf(a.w);
        o.u[4] = f2bf(b.x); o.u[5] = f2bf(b.y); o.u[6] = f2bf(b.z); o.u[7] = f2bf(b.w);
        ((u32x4*)xb)[i] = o.v;
    } else if (bid < 4864) {
        int idx = bid - 4096;               // 48 x 16 tiles
        transW_body(Wqkv, wqkvT, 3072, (idx % 48) * 64, (idx / 48) * 64, tid, t);
    } else {
        int idx = bid - 4864;               // 16 x 16 tiles
        transW_body(Wproj, wprojT, 1024, (idx % 16) * 64, (idx / 16) * 64, tid, t);
    }
}

// ---------------- GEMM: [8192][1024] x BT[Nd][1024] ----------------
// XCD-panel-blocked 1D grid: xcd = bid&7 owns M-tiles [xcd*8, xcd*8+8);
// within an XCD blocks walk B-panel-major.
// MODE 0: QKV -> q(*0.125*log2e)/k scattered as [bh][n][64];
//   v-blocks (nt>=16) transpose their 128x128 acc tile in LDS and store
//   v^T [bh][dh][n] as contiguous 256B runs (R6 lesson: direct scatter = 1
//   line per lane; this fused path saved ~15us vs separate transV pass, R11).
// MODE 1: proj -> out f32 [8192][1024] + bias
template <int MODE>
__global__ __launch_bounds__(256) void k_gemm(
    const uint16_t* __restrict__ A, const uint16_t* __restrict__ BT,
    const float* __restrict__ bias,
    uint16_t* __restrict__ qo, uint16_t* __restrict__ ko, uint16_t* __restrict__ vo,
    float* __restrict__ out) {
    __shared__ uint16_t smem[16640];        // a_lds[8192] + b_lds[8192]; v-epilogue reuses as [128][130]
    uint16_t* a_lds = smem;
    uint16_t* b_lds = smem + 8192;
    int tid = threadIdx.x;
    int w = tid >> 6, l = tid & 63;
    int l15 = l & 15, l4 = l >> 4;
    int bid = blockIdx.x;
    int mt = ((bid & 7) << 3) + ((bid >> 3) & 7);   // xcd*8 + local M index
    int nt = bid >> 6;                               // B-panel index
    int m0 = mt * 128, n0 = nt * 128;
    int wr = w >> 1, wc = w & 1;
    f32x4 acc[4][4] = {};

    for (int kt = 0; kt < 16; ++kt) {
#pragma unroll
        for (int i = 0; i < 4; ++i) {
            int c = i * 256 + w * 64 + l;
            int row = c >> 3, slot = c & 7;
            int kc = slot ^ (row & 7);
            gload16(A + (size_t)(m0 + row) * 1024 + kt * 64 + kc * 8,
                    a_lds + (size_t)(i * 256 + w * 64) * 8);
            gload16(BT + (size_t)(n0 + row) * 1024 + kt * 64 + kc * 8,
                    b_lds + (size_t)(i * 256 + w * 64) * 8);
        }
        __syncthreads();
#pragma unroll
        for (int kkk = 0; kkk < 2; ++kkk) {
            bf16x8 af[4], bfr[4];
#pragma unroll
            for (int i = 0; i < 4; ++i) {
                int row = wr * 64 + i * 16 + l15;
                af[i] = ld8(a_lds + row * 64 + ((kkk * 4 + l4) ^ (row & 7)) * 8);
                int rowb = wc * 64 + i * 16 + l15;
                bfr[i] = ld8(b_lds + rowb * 64 + ((kkk * 4 + l4) ^ (rowb & 7)) * 8);
            }
#pragma unroll
            for (int i = 0; i < 4; ++i)
#pragma unroll
                for (int j = 0; j < 4; ++j)
                    acc[i][j] = __builtin_amdgcn_mfma_f32_16x16x32_bf16(
                        af[i], bfr[j], acc[i][j], 0, 0, 0);
        }
        __syncthreads();
    }

    if constexpr (MODE == 0) {
        if (n0 >= 2048) {
            // ---- v-block: transpose 128x128 acc tile in LDS, store v^T coalesced ----
            // smem as [128 d][130] (row stride 130 words -> bank stride 2, light conflicts)
#pragma unroll
            for (int i = 0; i < 4; ++i)
#pragma unroll
                for (int j = 0; j < 4; ++j) {
                    int dl = wc * 64 + j * 16 + l15;
                    int ml = wr * 64 + i * 16 + l4 * 4;
                    union { uint16_t u[4]; uint2 v2; } pk;
#pragma unroll
                    for (int r = 0; r < 4; ++r) pk.u[r] = f2bf(acc[i][j][r]);
                    *(uint2*)&smem[dl * 130 + ml] = pk.v2;
                }
            __syncthreads();
            int b = m0 >> 11, nbase = m0 & 2047;
#pragma unroll
            for (int pass = 0; pass < 8; ++pass) {
                int dl = pass * 16 + (tid >> 4);          // 0..127
                int mloc = (tid & 15) * 8;                // 0..120
                u32x4 val = *(u32x4*)&smem[dl * 130 + mloc];
                int d = n0 + dl;                          // 2048..3071
                int h = (d >> 6) & 15, dh = d & 63;
                *(u32x4*)(vo + ((size_t)(b * 16 + h) * 64 + dh) * 2048 + nbase + mloc) = val;
            }
        } else {
#pragma unroll
            for (int i = 0; i < 4; ++i)
#pragma unroll
                for (int j = 0; j < 4; ++j) {
                    int d = n0 + wc * 64 + j * 16 + l15;
                    int s = d >> 10, h = (d >> 6) & 15, dh = d & 63;
                    uint16_t* dst0 = (s == 0) ? qo : ko;
                    // q pre-scaled by Dh^-0.5 * log2(e) so softmax runs in exp2 domain
                    float sc = (s == 0) ? 0.18033688011112042f : 1.0f;
#pragma unroll
                    for (int r = 0; r < 4; ++r) {
                        int m = m0 + wr * 64 + i * 16 + l4 * 4 + r;
                        int b = m >> 11, n = m & 2047;
                        dst0[((size_t)(b * 16 + h) * 2048 + n) * 64 + dh] = f2bf(acc[i][j][r] * sc);
                    }
                }
        }
    } else {
#pragma unroll
        for (int j = 0; j < 4; ++j) {
            int d = n0 + wc * 64 + j * 16 + l15;
            float bv = bias[d];
#pragma unroll
            for (int i = 0; i < 4; ++i)
#pragma unroll
                for (int r = 0; r < 4; ++r) {
                    int m = m0 + wr * 64 + i * 16 + l4 * 4 + r;
                    out[(size_t)m * 1024 + d] = acc[i][j][r] + bv;
                }
        }
    }
}

// ---------------- flash attention (no-max softmax, exp2 domain) ----------------
// R7-proven body (103.6 us, VGPR 84): split-barrier counted-vmcnt pipeline,
// K/V in LDS, scalar lsum, XCD swizzle. Single stj accumulator chain —
// R11's sA/sB ILP split cost +20 VGPR -> occupancy drop -> +16us. TLP rules here.
__global__ __launch_bounds__(256) void k_attn(
    const uint16_t* __restrict__ q, const uint16_t* __restrict__ kk_,
    const uint16_t* __restrict__ vt, uint16_t* __restrict__ o) {
    __shared__ uint16_t k_lds[2][64 * 64];
    __shared__ uint16_t v_lds[2][64 * 64];
    int tid = threadIdx.x;
    int w = tid >> 6, l = tid & 63;
    int l31 = l & 31, g = l >> 5;
    int bid = blockIdx.x;
    int slot = bid >> 3;
    int bh = (bid & 7) * 8 + (slot >> 4);
    int qt = slot & 15;
    int qrow = qt * 128 + w * 32 + l31;
    const uint16_t* qb = q + ((size_t)bh * 2048 + qrow) * 64;
    const uint16_t* kbase = kk_ + (size_t)bh * 2048 * 64;
    const uint16_t* vbase = vt + (size_t)bh * 64 * 2048;

    bf16x8 qf[4];
#pragma unroll
    for (int kv = 0; kv < 4; ++kv) qf[kv] = ld8(qb + kv * 16 + g * 8);

    // staging source pointers (lane-fixed, advanced by constants each tile)
    int c0 = w * 128 + l;
    int rr0 = c0 >> 3, sl0 = c0 & 7;
    int kc0 = sl0 ^ (rr0 & 7);
    int rr1 = rr0 + 8, kc1 = sl0 ^ (rr1 & 7);
    const uint16_t* kp0 = kbase + rr0 * 64 + kc0 * 8;
    const uint16_t* kp1 = kbase + rr1 * 64 + kc1 * 8;
    const uint16_t* vp0 = vbase + (size_t)rr0 * 2048 + kc0 * 8;
    const uint16_t* vp1 = vbase + (size_t)rr1 * 2048 + kc1 * 8;
    uint16_t* kd0 = k_lds[0] + w * 1024;
    uint16_t* kd1 = k_lds[1] + w * 1024;
    uint16_t* vd0 = v_lds[0] + w * 1024;
    uint16_t* vd1 = v_lds[1] + w * 1024;

    f32x16 oa[2] = {};
    float lsum = 0.f;

    auto stage = [&](uint16_t* kd, uint16_t* vd) {
        gload16(kp0, kd);       gload16(kp1, kd + 512);   // K first,
        gload16(vp0, vd);       gload16(vp1, vd + 512);   // V second (vmcnt order)
        kp0 += 4096; kp1 += 4096; vp0 += 64; vp1 += 64;
    };

    stage(kd0, vd0);   // tile 0 -> buf 0  (4 outstanding)

    auto body = [&](int t, const uint16_t* kb, const uint16_t* vb,
                    uint16_t* kdn, uint16_t* vdn) {
        // K(t) ready for all waves
        asm volatile("s_waitcnt vmcnt(2)\n\ts_barrier" ::: "memory");
        if (t < 31) stage(kdn, vdn);   // issue next tile ASAP (lands during compute)

        // S^T = K * Q^T, then P = exp2(S) in-register (32 keys at a time)
        bf16x8 pfrag[4];
#pragma unroll
        for (int j = 0; j < 2; ++j) {
            int key = j * 32 + l31;
            f32x16 stj = {};
            __builtin_amdgcn_s_setprio(1);
#pragma unroll
            for (int kv = 0; kv < 4; ++kv) {
                bf16x8 kf = ld8(kb + key * 64 + ((2 * kv + g) ^ (key & 7)) * 8);
                stj = __builtin_amdgcn_mfma_f32_32x32x16_bf16(kf, qf[kv], stj, 0, 0, 0);
            }
            __builtin_amdgcn_s_setprio(0);
#pragma unroll
            for (int h = 0; h < 2; ++h) {
                float e[8];
#pragma unroll
                for (int jj = 0; jj < 8; ++jj) e[jj] = exp2_fast(stj[h * 8 + jj]);
                lsum += ((e[0] + e[1]) + (e[2] + e[3])) + ((e[4] + e[5]) + (e[6] + e[7]));
                uint32_t a0 = cvtpk(e[0], e[1]), a1 = cvtpk(e[2], e[3]);
                uint32_t b0 = cvtpk(e[4], e[5]), b1 = cvtpk(e[6], e[7]);
                auto r0 = __builtin_amdgcn_permlane32_swap(a0, b0, false, false);
                auto r1 = __builtin_amdgcn_permlane32_swap(a1, b1, false, false);
                u32x4 f;
                f[0] = r0[0]; f[1] = r1[0]; f[2] = r0[1]; f[3] = r1[1];
                pfrag[j * 2 + h] = __builtin_bit_cast(bf16x8, f);
            }
        }

        // V(t) ready for all waves
        if (t < 31) asm volatile("s_waitcnt vmcnt(4)\n\ts_barrier" ::: "memory");
        else        asm volatile("s_waitcnt vmcnt(0)\n\ts_barrier" ::: "memory");

        // O^T += V^T * P^T
        __builtin_amdgcn_s_setprio(1);
#pragma unroll
        for (int kv = 0; kv < 4; ++kv) {
#pragma unroll
            for (int dt = 0; dt < 2; ++dt) {
                int dh = dt * 32 + l31;
                bf16x8 vf = ld8(vb + dh * 64 + ((2 * kv + g) ^ (dh & 7)) * 8);
                oa[dt] = __builtin_amdgcn_mfma_f32_32x32x16_bf16(vf, pfrag[kv], oa[dt], 0, 0, 0);
            }
        }
        __builtin_amdgcn_s_setprio(0);
    };

    for (int kt = 0; kt < 32; kt += 2) {
        body(kt,     k_lds[0], v_lds[0], kd1, vd1);
        body(kt + 1, k_lds[1], v_lds[1], kd0, vd0);
    }

    float ltot = lsum + __shfl_xor(lsum, 32, 64);
    float inv = 1.0f / ltot;
    int b = bh >> 4, h = bh & 15;
    uint16_t* ob = o + ((size_t)(b * 2048 + qrow)) * 1024 + h * 64;
#pragma unroll
    for (int dt = 0; dt < 2; ++dt)
#pragma unroll
        for (int rq = 0; rq < 4; ++rq) {
            union { uint16_t u[4]; uint2 v; } pk;
#pragma unroll
            for (int rr = 0; rr < 4; ++rr) pk.u[rr] = f2bf(oa[dt][rq * 4 + rr] * inv);
            int dh0 = dt * 32 + rq * 8 + g * 4;
            *(uint2*)(ob + dh0) = pk.v;
        }
}

extern "C" void kernel_launch(void* const* d_in, const int* in_sizes, int n_in,
                              void* d_out, int out_size, void* d_ws, size_t ws_size,
                              hipStream_t stream) {
    const float* x     = (const float*)d_in[0];
    // d_in[1] = xpos : unused by the reference
    const float* Wqkv  = (const float*)d_in[2];
    const float* Wproj = (const float*)d_in[3];
    const float* bproj = (const float*)d_in[4];
    float* out = (float*)d_out;

    char* ws = (char*)d_ws;
    uint16_t* xb     = (uint16_t*)(ws);                         // 16.78 MB
    uint16_t* wqkvT  = (uint16_t*)(ws + 16777216);              //  6.29 MB
    uint16_t* wprojT = (uint16_t*)(ws + 23068672);              //  2.10 MB
    uint16_t* qws    = (uint16_t*)(ws + 25165824);              // 16.78 MB
    uint16_t* kws    = (uint16_t*)(ws + 41943040);              // 16.78 MB
    uint16_t* vT     = (uint16_t*)(ws + 58720256);              // 16.78 MB (total ~75.5 MB)
    uint16_t* attnout = xb;  // xb is dead after QKV GEMM

    k_prep<<<dim3(5120), dim3(256), 0, stream>>>(x, xb, Wqkv, wqkvT, Wproj, wprojT);
    k_gemm<0><<<dim3(1536), dim3(256), 0, stream>>>(xb, wqkvT, nullptr, qws, kws, vT, nullptr);
    k_attn<<<dim3(1024), dim3(256), 0, stream>>>(qws, kws, vT, attnout);
    k_gemm<1><<<dim3(512), dim3(256), 0, stream>>>(attnout, wprojT, bproj, nullptr, nullptr, nullptr, out);
}

// Round 15
// 204.075 us; speedup vs baseline: 1.0334x; 1.0015x over previous
//
#include <hip/hip_runtime.h>
#include <stdint.h>

#define DEVINL __device__ __forceinline__

typedef __bf16 bf16x8 __attribute__((ext_vector_type(8)));
typedef float f32x4 __attribute__((ext_vector_type(4)));
typedef float f32x16 __attribute__((ext_vector_type(16)));
typedef uint32_t u32x4 __attribute__((ext_vector_type(4)));

DEVINL uint16_t f2bf(float f) {
    uint32_t u = __builtin_bit_cast(uint32_t, f);
    uint32_t r = (u + 0x7FFFu + ((u >> 16) & 1u)) >> 16;
    return (uint16_t)r;
}

DEVINL bf16x8 ld8(const uint16_t* p) {
    u32x4 v = *(const u32x4*)p;
    return __builtin_bit_cast(bf16x8, v);
}

DEVINL void gload16(const void* g, void* l) {
    __builtin_amdgcn_global_load_lds(
        (const __attribute__((address_space(1))) uint32_t*)g,
        (__attribute__((address_space(3))) uint32_t*)l, 16, 0, 0);
}

DEVINL uint32_t cvtpk(float lo, float hi) {
    uint32_t r;
    asm("v_cvt_pk_bf16_f32 %0, %1, %2" : "=v"(r) : "v"(lo), "v"(hi));
    return r;
}

DEVINL float exp2_fast(float x) {
    float r;
    asm("v_exp_f32 %0, %1" : "=v"(r) : "v"(x));
    return r;
}

// ---------------- fused prep: cvt x -> bf16 ; transpose+cvt Wqkv, Wproj ----------------
DEVINL void transW_body(const float* __restrict__ W, uint16_t* __restrict__ WT,
                        int Nn, int n0, int k0, int tid, uint16_t* t) {
#pragma unroll
    for (int i = 0; i < 4; ++i) {
        int c = tid + i * 256;              // 1024 float4 chunks
        int kr = c >> 4, nc = c & 15;
        float4 v = *(const float4*)(W + (size_t)(k0 + kr) * Nn + n0 + nc * 4);
        t[(nc * 4 + 0) * 65 + kr] = f2bf(v.x);
        t[(nc * 4 + 1) * 65 + kr] = f2bf(v.y);
        t[(nc * 4 + 2) * 65 + kr] = f2bf(v.z);
        t[(nc * 4 + 3) * 65 + kr] = f2bf(v.w);
    }
    __syncthreads();
#pragma unroll
    for (int i = 0; i < 2; ++i) {
        int c = tid + i * 256;              // 512 chunks of 8 bf16
        int nr = c >> 3, kc = c & 7;
        union { uint16_t u[8]; u32x4 v; } o;
#pragma unroll
        for (int j = 0; j < 8; ++j) o.u[j] = t[nr * 65 + kc * 8 + j];
        *(u32x4*)(WT + (size_t)(n0 + nr) * 1024 + k0 + kc * 8) = o.v;
    }
}

__global__ void k_prep(const float* __restrict__ x, uint16_t* __restrict__ xb,
                       const float* __restrict__ Wqkv, uint16_t* __restrict__ wqkvT,
                       const float* __restrict__ Wproj, uint16_t* __restrict__ wprojT) {
    __shared__ uint16_t t[64 * 65];
    int bid = blockIdx.x;
    int tid = threadIdx.x;
    if (bid < 4096) {
        int i = bid * 256 + tid;            // 1048576 chunks of 8 floats
        const float4* src = (const float4*)x + (size_t)i * 2;
        float4 a = src[0], b = src[1];
        union { uint16_t u[8]; u32x4 v; } o;
        o.u[0] = f2bf(a.x); o.u[1] = f2bf(a.y); o.u[2] = f2bf(a.z); o.u[3] = f2bf(a.w);
        o.u[4] = f2bf(b.x); o.u[5] = f2bf(b.y); o.u[6] = f2bf(b.z); o.u[7] = f2bf(b.w);
        ((u32x4*)xb)[i] = o.v;
    } else if (bid < 4864) {
        int idx = bid - 4096;               // 48 x 16 tiles
        transW_body(Wqkv, wqkvT, 3072, (idx % 48) * 64, (idx / 48) * 64, tid, t);
    } else {
        int idx = bid - 4864;               // 16 x 16 tiles
        transW_body(Wproj, wprojT, 1024, (idx % 16) * 64, (idx / 16) * 64, tid, t);
    }
}

// ---------------- GEMM: [8192][1024] x BT[Nd][1024] ----------------
// XCD-panel-blocked 1D grid: xcd = bid&7 owns M-tiles [xcd*8, xcd*8+8);
// within an XCD blocks walk B-panel-major.
// MODE 0: QKV. All epilogues retile through LDS for coalesced 16B stores:
//   q/k blocks (n0<2048): LDS[m][d] (no transpose) -> [bh][n][64] rows as
//     128B-contiguous runs (was 32B segments: 4 n x 16 dh scatter).
//   v blocks (n0>=2048): LDS transpose -> v^T [bh][dh][n] 256B runs (R11 win).
// MODE 1: proj -> out f32 [8192][1024] + bias
template <int MODE>
__global__ __launch_bounds__(256) void k_gemm(
    const uint16_t* __restrict__ A, const uint16_t* __restrict__ BT,
    const float* __restrict__ bias,
    uint16_t* __restrict__ qo, uint16_t* __restrict__ ko, uint16_t* __restrict__ vo,
    float* __restrict__ out) {
    __shared__ uint16_t smem[16640];        // a_lds[8192] + b_lds[8192]; epilogue reuses as [128][130]
    uint16_t* a_lds = smem;
    uint16_t* b_lds = smem + 8192;
    int tid = threadIdx.x;
    int w = tid >> 6, l = tid & 63;
    int l15 = l & 15, l4 = l >> 4;
    int bid = blockIdx.x;
    int mt = ((bid & 7) << 3) + ((bid >> 3) & 7);   // xcd*8 + local M index
    int nt = bid >> 6;                               // B-panel index
    int m0 = mt * 128, n0 = nt * 128;
    int wr = w >> 1, wc = w & 1;
    f32x4 acc[4][4] = {};

    for (int kt = 0; kt < 16; ++kt) {
#pragma unroll
        for (int i = 0; i < 4; ++i) {
            int c = i * 256 + w * 64 + l;
            int row = c >> 3, slot = c & 7;
            int kc = slot ^ (row & 7);
            gload16(A + (size_t)(m0 + row) * 1024 + kt * 64 + kc * 8,
                    a_lds + (size_t)(i * 256 + w * 64) * 8);
            gload16(BT + (size_t)(n0 + row) * 1024 + kt * 64 + kc * 8,
                    b_lds + (size_t)(i * 256 + w * 64) * 8);
        }
        __syncthreads();
#pragma unroll
        for (int kkk = 0; kkk < 2; ++kkk) {
            bf16x8 af[4], bfr[4];
#pragma unroll
            for (int i = 0; i < 4; ++i) {
                int row = wr * 64 + i * 16 + l15;
                af[i] = ld8(a_lds + row * 64 + ((kkk * 4 + l4) ^ (row & 7)) * 8);
                int rowb = wc * 64 + i * 16 + l15;
                bfr[i] = ld8(b_lds + rowb * 64 + ((kkk * 4 + l4) ^ (rowb & 7)) * 8);
            }
#pragma unroll
            for (int i = 0; i < 4; ++i)
#pragma unroll
                for (int j = 0; j < 4; ++j)
                    acc[i][j] = __builtin_amdgcn_mfma_f32_16x16x32_bf16(
                        af[i], bfr[j], acc[i][j], 0, 0, 0);
        }
        __syncthreads();
    }

    if constexpr (MODE == 0) {
        int b = m0 >> 11, nbase = m0 & 2047;
        if (n0 >= 2048) {
            // ---- v-block: transpose 128x128 acc tile in LDS, store v^T coalesced ----
            // smem as [128 d][130] (row stride 130 words -> bank stride 2, light conflicts)
#pragma unroll
            for (int i = 0; i < 4; ++i)
#pragma unroll
                for (int j = 0; j < 4; ++j) {
                    int dl = wc * 64 + j * 16 + l15;
                    int ml = wr * 64 + i * 16 + l4 * 4;
                    union { uint16_t u[4]; uint2 v2; } pk;
#pragma unroll
                    for (int r = 0; r < 4; ++r) pk.u[r] = f2bf(acc[i][j][r]);
                    *(uint2*)&smem[dl * 130 + ml] = pk.v2;
                }
            __syncthreads();
#pragma unroll
            for (int pass = 0; pass < 8; ++pass) {
                int dl = pass * 16 + (tid >> 4);          // 0..127
                int mloc = (tid & 15) * 8;                // 0..120
                u32x4 val = *(u32x4*)&smem[dl * 130 + mloc];
                int d = n0 + dl;                          // 2048..3071
                int h = (d >> 6) & 15, dh = d & 63;
                *(u32x4*)(vo + ((size_t)(b * 16 + h) * 64 + dh) * 2048 + nbase + mloc) = val;
            }
        } else {
            // ---- q/k block: retile acc[m][d] through LDS (no transpose) so each
            // 16B store lands in 128B-contiguous head-rows of [bh][n][64] ----
            float sc = (n0 < 1024) ? 0.18033688011112042f : 1.0f;  // q pre-scale (exp2 domain)
            uint16_t* dst0 = (n0 < 1024) ? qo : ko;
#pragma unroll
            for (int i = 0; i < 4; ++i)
#pragma unroll
                for (int j = 0; j < 4; ++j) {
                    int dloc = wc * 64 + j * 16 + l15;
                    int mloc = wr * 64 + i * 16 + l4 * 4;
#pragma unroll
                    for (int r = 0; r < 4; ++r)
                        smem[(mloc + r) * 130 + dloc] = f2bf(acc[i][j][r] * sc);
                }
            __syncthreads();
#pragma unroll
            for (int pass = 0; pass < 8; ++pass) {
                int ml = pass * 16 + (tid >> 4);          // 0..127 (local n)
                int dl = (tid & 15) * 8;                  // 0..120 (local d, 8-chunk)
                u32x4 val = *(u32x4*)&smem[ml * 130 + dl];
                int d = n0 + dl;                          // chunk stays within one head
                int h = (d >> 6) & 15, dh = d & 63;
                *(u32x4*)(dst0 + ((size_t)(b * 16 + h) * 2048 + nbase + ml) * 64 + dh) = val;
            }
        }
    } else {
#pragma unroll
        for (int j = 0; j < 4; ++j) {
            int d = n0 + wc * 64 + j * 16 + l15;
            float bv = bias[d];
#pragma unroll
            for (int i = 0; i < 4; ++i)
#pragma unroll
                for (int r = 0; r < 4; ++r) {
                    int m = m0 + wr * 64 + i * 16 + l4 * 4 + r;
                    out[(size_t)m * 1024 + d] = acc[i][j][r] + bv;
                }
        }
    }
}

// ---------------- flash attention (no-max softmax, exp2 domain) ----------------
// R12-proven body EXACT (103.5 us, VGPR 84): 4-wave blocks, split-barrier
// counted-vmcnt pipeline, K/V in LDS, scalar lsum, XCD swizzle.
// (R13/R14 8-wave variants both failed correctness ~6e-2 with two different
// wait structures; bug in the 8-wave staging geometry unresolved -> frozen.)
__global__ __launch_bounds__(256) void k_attn(
    const uint16_t* __restrict__ q, const uint16_t* __restrict__ kk_,
    const uint16_t* __restrict__ vt, uint16_t* __restrict__ o) {
    __shared__ uint16_t k_lds[2][64 * 64];
    __shared__ uint16_t v_lds[2][64 * 64];
    int tid = threadIdx.x;
    int w = tid >> 6, l = tid & 63;
    int l31 = l & 31, g = l >> 5;
    int bid = blockIdx.x;
    int slot = bid >> 3;
    int bh = (bid & 7) * 8 + (slot >> 4);
    int qt = slot & 15;
    int qrow = qt * 128 + w * 32 + l31;
    const uint16_t* qb = q + ((size_t)bh * 2048 + qrow) * 64;
    const uint16_t* kbase = kk_ + (size_t)bh * 2048 * 64;
    const uint16_t* vbase = vt + (size_t)bh * 64 * 2048;

    bf16x8 qf[4];
#pragma unroll
    for (int kv = 0; kv < 4; ++kv) qf[kv] = ld8(qb + kv * 16 + g * 8);

    // staging source pointers (lane-fixed, advanced by constants each tile)
    int c0 = w * 128 + l;
    int rr0 = c0 >> 3, sl0 = c0 & 7;
    int kc0 = sl0 ^ (rr0 & 7);
    int rr1 = rr0 + 8, kc1 = sl0 ^ (rr1 & 7);
    const uint16_t* kp0 = kbase + rr0 * 64 + kc0 * 8;
    const uint16_t* kp1 = kbase + rr1 * 64 + kc1 * 8;
    const uint16_t* vp0 = vbase + (size_t)rr0 * 2048 + kc0 * 8;
    const uint16_t* vp1 = vbase + (size_t)rr1 * 2048 + kc1 * 8;
    uint16_t* kd0 = k_lds[0] + w * 1024;
    uint16_t* kd1 = k_lds[1] + w * 1024;
    uint16_t* vd0 = v_lds[0] + w * 1024;
    uint16_t* vd1 = v_lds[1] + w * 1024;

    f32x16 oa[2] = {};
    float lsum = 0.f;

    auto stage = [&](uint16_t* kd, uint16_t* vd) {
        gload16(kp0, kd);       gload16(kp1, kd + 512);   // K first,
        gload16(vp0, vd);       gload16(vp1, vd + 512);   // V second (vmcnt order)
        kp0 += 4096; kp1 += 4096; vp0 += 64; vp1 += 64;
    };

    stage(kd0, vd0);   // tile 0 -> buf 0  (4 outstanding)

    auto body = [&](int t, const uint16_t* kb, const uint16_t* vb,
                    uint16_t* kdn, uint16_t* vdn) {
        // K(t) ready for all waves
        asm volatile("s_waitcnt vmcnt(2)\n\ts_barrier" ::: "memory");
        if (t < 31) stage(kdn, vdn);   // issue next tile ASAP (lands during compute)

        // S^T = K * Q^T, then P = exp2(S) in-register (32 keys at a time)
        bf16x8 pfrag[4];
#pragma unroll
        for (int j = 0; j < 2; ++j) {
            int key = j * 32 + l31;
            f32x16 stj = {};
            __builtin_amdgcn_s_setprio(1);
#pragma unroll
            for (int kv = 0; kv < 4; ++kv) {
                bf16x8 kf = ld8(kb + key * 64 + ((2 * kv + g) ^ (key & 7)) * 8);
                stj = __builtin_amdgcn_mfma_f32_32x32x16_bf16(kf, qf[kv], stj, 0, 0, 0);
            }
            __builtin_amdgcn_s_setprio(0);
#pragma unroll
            for (int h = 0; h < 2; ++h) {
                float e[8];
#pragma unroll
                for (int jj = 0; jj < 8; ++jj) e[jj] = exp2_fast(stj[h * 8 + jj]);
                lsum += ((e[0] + e[1]) + (e[2] + e[3])) + ((e[4] + e[5]) + (e[6] + e[7]));
                uint32_t a0 = cvtpk(e[0], e[1]), a1 = cvtpk(e[2], e[3]);
                uint32_t b0 = cvtpk(e[4], e[5]), b1 = cvtpk(e[6], e[7]);
                auto r0 = __builtin_amdgcn_permlane32_swap(a0, b0, false, false);
                auto r1 = __builtin_amdgcn_permlane32_swap(a1, b1, false, false);
                u32x4 f;
                f[0] = r0[0]; f[1] = r1[0]; f[2] = r0[1]; f[3] = r1[1];
                pfrag[j * 2 + h] = __builtin_bit_cast(bf16x8, f);
            }
        }

        // V(t) ready for all waves
        if (t < 31) asm volatile("s_waitcnt vmcnt(4)\n\ts_barrier" ::: "memory");
        else        asm volatile("s_waitcnt vmcnt(0)\n\ts_barrier" ::: "memory");

        // O^T += V^T * P^T
        __builtin_amdgcn_s_setprio(1);
#pragma unroll
        for (int kv = 0; kv < 4; ++kv) {
#pragma unroll
            for (int dt = 0; dt < 2; ++dt) {
                int dh = dt * 32 + l31;
                bf16x8 vf = ld8(vb + dh * 64 + ((2 * kv + g) ^ (dh & 7)) * 8);
                oa[dt] = __builtin_amdgcn_mfma_f32_32x32x16_bf16(vf, pfrag[kv], oa[dt], 0, 0, 0);
            }
        }
        __builtin_amdgcn_s_setprio(0);
    };

    for (int kt = 0; kt < 32; kt += 2) {
        body(kt,     k_lds[0], v_lds[0], kd1, vd1);
        body(kt + 1, k_lds[1], v_lds[1], kd0, vd0);
    }

    float ltot = lsum + __shfl_xor(lsum, 32, 64);
    float inv = 1.0f / ltot;
    int b = bh >> 4, h = bh & 15;
    uint16_t* ob = o + ((size_t)(b * 2048 + qrow)) * 1024 + h * 64;
#pragma unroll
    for (int dt = 0; dt < 2; ++dt)
#pragma unroll
        for (int rq = 0; rq < 4; ++rq) {
            union { uint16_t u[4]; uint2 v; } pk;
#pragma unroll
            for (int rr = 0; rr < 4; ++rr) pk.u[rr] = f2bf(oa[dt][rq * 4 + rr] * inv);
            int dh0 = dt * 32 + rq * 8 + g * 4;
            *(uint2*)(ob + dh0) = pk.v;
        }
}

extern "C" void kernel_launch(void* const* d_in, const int* in_sizes, int n_in,
                              void* d_out, int out_size, void* d_ws, size_t ws_size,
                              hipStream_t stream) {
    const float* x     = (const float*)d_in[0];
    // d_in[1] = xpos : unused by the reference
    const float* Wqkv  = (const float*)d_in[2];
    const float* Wproj = (const float*)d_in[3];
    const float* bproj = (const float*)d_in[4];
    float* out = (float*)d_out;

    char* ws = (char*)d_ws;
    uint16_t* xb     = (uint16_t*)(ws);                         // 16.78 MB
    uint16_t* wqkvT  = (uint16_t*)(ws + 16777216);              //  6.29 MB
    uint16_t* wprojT = (uint16_t*)(ws + 23068672);              //  2.10 MB
    uint16_t* qws    = (uint16_t*)(ws + 25165824);              // 16.78 MB
    uint16_t* kws    = (uint16_t*)(ws + 41943040);              // 16.78 MB
    uint16_t* vT     = (uint16_t*)(ws + 58720256);              // 16.78 MB (total ~75.5 MB)
    uint16_t* attnout = xb;  // xb is dead after QKV GEMM

    k_prep<<<dim3(5120), dim3(256), 0, stream>>>(x, xb, Wqkv, wqkvT, Wproj, wprojT);
    k_gemm<0><<<dim3(1536), dim3(256), 0, stream>>>(xb, wqkvT, nullptr, qws, kws, vT, nullptr);
    k_attn<<<dim3(1024), dim3(256), 0, stream>>>(qws, kws, vT, attnout);
    k_gemm<1><<<dim3(512), dim3(256), 0, stream>>>(attnout, wprojT, bproj, nullptr, nullptr, nullptr, out);
}

// Round 16
// 195.937 us; speedup vs baseline: 1.0763x; 1.0415x over previous
//
#include <hip/hip_runtime.h>
#include <stdint.h>

#define DEVINL __device__ __forceinline__

typedef __bf16 bf16x8 __attribute__((ext_vector_type(8)));
typedef float f32x4 __attribute__((ext_vector_type(4)));
typedef float f32x16 __attribute__((ext_vector_type(16)));
typedef uint32_t u32x4 __attribute__((ext_vector_type(4)));

DEVINL uint16_t f2bf(float f) {
    uint32_t u = __builtin_bit_cast(uint32_t, f);
    uint32_t r = (u + 0x7FFFu + ((u >> 16) & 1u)) >> 16;
    return (uint16_t)r;
}

DEVINL bf16x8 ld8(const uint16_t* p) {
    u32x4 v = *(const u32x4*)p;
    return __builtin_bit_cast(bf16x8, v);
}

DEVINL void gload16(const void* g, void* l) {
    __builtin_amdgcn_global_load_lds(
        (const __attribute__((address_space(1))) uint32_t*)g,
        (__attribute__((address_space(3))) uint32_t*)l, 16, 0, 0);
}

DEVINL uint32_t cvtpk(float lo, float hi) {
    uint32_t r;
    asm("v_cvt_pk_bf16_f32 %0, %1, %2" : "=v"(r) : "v"(lo), "v"(hi));
    return r;
}

DEVINL float exp2_fast(float x) {
    float r;
    asm("v_exp_f32 %0, %1" : "=v"(r) : "v"(x));
    return r;
}

// ---------------- fused prep: cvt x -> bf16 ; transpose+cvt Wqkv, Wproj ----------------
DEVINL void transW_body(const float* __restrict__ W, uint16_t* __restrict__ WT,
                        int Nn, int n0, int k0, int tid, uint16_t* t) {
#pragma unroll
    for (int i = 0; i < 4; ++i) {
        int c = tid + i * 256;              // 1024 float4 chunks
        int kr = c >> 4, nc = c & 15;
        float4 v = *(const float4*)(W + (size_t)(k0 + kr) * Nn + n0 + nc * 4);
        t[(nc * 4 + 0) * 65 + kr] = f2bf(v.x);
        t[(nc * 4 + 1) * 65 + kr] = f2bf(v.y);
        t[(nc * 4 + 2) * 65 + kr] = f2bf(v.z);
        t[(nc * 4 + 3) * 65 + kr] = f2bf(v.w);
    }
    __syncthreads();
#pragma unroll
    for (int i = 0; i < 2; ++i) {
        int c = tid + i * 256;              // 512 chunks of 8 bf16
        int nr = c >> 3, kc = c & 7;
        union { uint16_t u[8]; u32x4 v; } o;
#pragma unroll
        for (int j = 0; j < 8; ++j) o.u[j] = t[nr * 65 + kc * 8 + j];
        *(u32x4*)(WT + (size_t)(n0 + nr) * 1024 + k0 + kc * 8) = o.v;
    }
}

__global__ void k_prep(const float* __restrict__ x, uint16_t* __restrict__ xb,
                       const float* __restrict__ Wqkv, uint16_t* __restrict__ wqkvT,
                       const float* __restrict__ Wproj, uint16_t* __restrict__ wprojT) {
    __shared__ uint16_t t[64 * 65];
    int bid = blockIdx.x;
    int tid = threadIdx.x;
    if (bid < 4096) {
        int i = bid * 256 + tid;            // 1048576 chunks of 8 floats
        const float4* src = (const float4*)x + (size_t)i * 2;
        float4 a = src[0], b = src[1];
        union { uint16_t u[8]; u32x4 v; } o;
        o.u[0] = f2bf(a.x); o.u[1] = f2bf(a.y); o.u[2] = f2bf(a.z); o.u[3] = f2bf(a.w);
        o.u[4] = f2bf(b.x); o.u[5] = f2bf(b.y); o.u[6] = f2bf(b.z); o.u[7] = f2bf(b.w);
        ((u32x4*)xb)[i] = o.v;
    } else if (bid < 4864) {
        int idx = bid - 4096;               // 48 x 16 tiles
        transW_body(Wqkv, wqkvT, 3072, (idx % 48) * 64, (idx / 48) * 64, tid, t);
    } else {
        int idx = bid - 4864;               // 16 x 16 tiles
        transW_body(Wproj, wprojT, 1024, (idx % 16) * 64, (idx / 16) * 64, tid, t);
    }
}

// ---------------- GEMM: [8192][1024] x BT[Nd][1024], BM=256 BN=128 BK=64 ----------------
// 8 waves (512 thr), double-buffered dynamic LDS 96KB:
//   A[buf][half]: buf*16384 + half*8192 (2 halves x 128 rows x 64K, slot-swizzled)
//   B[buf]:       32768 + buf*8192     (128 rows x 64K, slot-swizzled)
// Stagger-by-one pipeline, zero intra-step barriers:
//   prologue STAGE(0,buf0); vmcnt(0)+bar
//   step s: STAGE(s+1 -> other buf)   [WAR ok: that buf's reads ended at the
//            barrier closing step s-1]  -> compute s -> vmcnt(0)+bar [RAW:
//            s+1's 6 loads had a full compute step (~2000cyc MFMA) of cover].
// Wave w: wr=w>>2 (M-half, 128 rows), wc=w&3 (N-quarter, 32 cols); 8x2 frags.
// MODE 0: QKV. nt 0..7 q (scaled), 8..15 k, 16..23 v (LDS-transposed to v^T).
// MODE 1: proj -> out f32 + bias (nt 0..7).
template <int MODE>
__global__ __launch_bounds__(512) void k_gemm(
    const uint16_t* __restrict__ A, const uint16_t* __restrict__ BT,
    const float* __restrict__ bias,
    uint16_t* __restrict__ qo, uint16_t* __restrict__ ko, uint16_t* __restrict__ vo,
    float* __restrict__ out) {
    extern __shared__ uint16_t lds[];
    int tid = threadIdx.x;
    int w = tid >> 6, l = tid & 63;
    int l15 = l & 15, l4 = l >> 4;
    int wr = w >> 2, wc = w & 3;
    int bid = blockIdx.x;
    int mt = (bid & 7) * 4 + ((bid >> 3) & 3);   // XCD-chunked M
    int nt = bid >> 5;                            // B-panel index
    int m0 = mt * 256, n0 = nt * 128;

    // staging source pointers: thread covers row r0 (+64*q), swizzled chunk kc
    int r0 = tid >> 3, sl0 = tid & 7;
    int kc = sl0 ^ (r0 & 7);
    const uint16_t* pA = A + (size_t)(m0 + r0) * 1024 + kc * 8;
    const uint16_t* pB = BT + (size_t)(n0 + r0) * 1024 + kc * 8;
    int wofs = w * 512;

    f32x4 acc[8][2] = {};

    auto stageK = [&](int ks, int abA, int abB) {
#pragma unroll
        for (int q = 0; q < 4; ++q)          // A: 4 x 64-row groups
            gload16(pA + q * 65536 + ks * 64, lds + abA + q * 4096 + wofs);
#pragma unroll
        for (int li = 0; li < 2; ++li)       // B: 2 x 64-row groups
            gload16(pB + li * 65536 + ks * 64, lds + abB + li * 4096 + wofs);
    };

    auto computeK = [&](int abA, int abB) {
        const uint16_t* Ah = lds + abA + wr * 8192;
        const uint16_t* Bb = lds + abB;
#pragma unroll
        for (int kk = 0; kk < 2; ++kk) {
            int ch = ((kk * 4 + l4) ^ (l15 & 7)) * 8;
            bf16x8 af[8], bf[2];
#pragma unroll
            for (int fi = 0; fi < 8; ++fi)
                af[fi] = ld8(Ah + (fi * 16 + l15) * 64 + ch);
#pragma unroll
            for (int fj = 0; fj < 2; ++fj)
                bf[fj] = ld8(Bb + (wc * 32 + fj * 16 + l15) * 64 + ch);
            __builtin_amdgcn_s_setprio(1);
#pragma unroll
            for (int fi = 0; fi < 8; ++fi)
#pragma unroll
                for (int fj = 0; fj < 2; ++fj)
                    acc[fi][fj] = __builtin_amdgcn_mfma_f32_16x16x32_bf16(
                        af[fi], bf[fj], acc[fi][fj], 0, 0, 0);
            __builtin_amdgcn_s_setprio(0);
        }
    };

    stageK(0, 0, 32768);
    asm volatile("s_waitcnt vmcnt(0)\n\ts_barrier" ::: "memory");
    for (int s = 0; s < 16; s += 2) {
        if (s + 1 < 16) stageK(s + 1, 16384, 40960);
        computeK(0, 32768);
        asm volatile("s_waitcnt vmcnt(0)\n\ts_barrier" ::: "memory");
        if (s + 2 < 16) stageK(s + 2, 0, 32768);
        computeK(16384, 40960);
        asm volatile("s_waitcnt vmcnt(0)\n\ts_barrier" ::: "memory");
    }

    if constexpr (MODE == 0) {
        int b = m0 >> 11, nbase = m0 & 2047;
        if (n0 >= 2048) {
            // ---- v-block: transpose 256x128 acc tile in LDS -> v^T [bh][dh][n] ----
            // lds as [128 d][264] (row stride 264 elems keeps 16B alignment)
#pragma unroll
            for (int fi = 0; fi < 8; ++fi)
#pragma unroll
                for (int fj = 0; fj < 2; ++fj) {
                    int dl = wc * 32 + fj * 16 + l15;
                    int ml = wr * 128 + fi * 16 + l4 * 4;
                    union { uint16_t u[4]; uint2 v2; } pk;
#pragma unroll
                    for (int r = 0; r < 4; ++r) pk.u[r] = f2bf(acc[fi][fj][r]);
                    *(uint2*)&lds[dl * 264 + ml] = pk.v2;
                }
        __syncthreads();
#pragma unroll
            for (int it = 0; it < 8; ++it) {
                int idx = it * 512 + tid;
                int row = idx >> 5, col = (idx & 31) * 8;   // 128 x 256 in 16B chunks
                u32x4 val = *(u32x4*)&lds[row * 264 + col];
                int dv = (n0 - 2048) + row;
                int h = dv >> 6, dh = dv & 63;
                *(u32x4*)(vo + ((size_t)(b * 16 + h) * 64 + dh) * 2048 + nbase + col) = val;
            }
        } else {
            float sc = (n0 < 1024) ? 0.18033688011112042f : 1.0f;  // q exp2-domain prescale
            uint16_t* dst0 = (n0 < 1024) ? qo : ko;
#pragma unroll
            for (int fi = 0; fi < 8; ++fi)
#pragma unroll
                for (int fj = 0; fj < 2; ++fj) {
                    int d = n0 + wc * 32 + fj * 16 + l15;
                    int h = (d >> 6) & 15, dh = d & 63;
#pragma unroll
                    for (int r = 0; r < 4; ++r) {
                        int n = nbase + wr * 128 + fi * 16 + l4 * 4 + r;
                        dst0[((size_t)(b * 16 + h) * 2048 + n) * 64 + dh] = f2bf(acc[fi][fj][r] * sc);
                    }
                }
        }
    } else {
#pragma unroll
        for (int fj = 0; fj < 2; ++fj) {
            int d = n0 + wc * 32 + fj * 16 + l15;
            float bv = bias[d];
#pragma unroll
            for (int fi = 0; fi < 8; ++fi)
#pragma unroll
                for (int r = 0; r < 4; ++r) {
                    int m = m0 + wr * 128 + fi * 16 + l4 * 4 + r;
                    out[(size_t)m * 1024 + d] = acc[fi][fj][r] + bv;
                }
        }
    }
}

// ---------------- flash attention (no-max softmax, exp2 domain) ----------------
// R12-proven body EXACT (103.5 us, VGPR 84): 4-wave blocks, split-barrier
// counted-vmcnt pipeline, K/V in LDS, scalar lsum, XCD swizzle. FROZEN.
__global__ __launch_bounds__(256) void k_attn(
    const uint16_t* __restrict__ q, const uint16_t* __restrict__ kk_,
    const uint16_t* __restrict__ vt, uint16_t* __restrict__ o) {
    __shared__ uint16_t k_lds[2][64 * 64];
    __shared__ uint16_t v_lds[2][64 * 64];
    int tid = threadIdx.x;
    int w = tid >> 6, l = tid & 63;
    int l31 = l & 31, g = l >> 5;
    int bid = blockIdx.x;
    int slot = bid >> 3;
    int bh = (bid & 7) * 8 + (slot >> 4);
    int qt = slot & 15;
    int qrow = qt * 128 + w * 32 + l31;
    const uint16_t* qb = q + ((size_t)bh * 2048 + qrow) * 64;
    const uint16_t* kbase = kk_ + (size_t)bh * 2048 * 64;
    const uint16_t* vbase = vt + (size_t)bh * 64 * 2048;

    bf16x8 qf[4];
#pragma unroll
    for (int kv = 0; kv < 4; ++kv) qf[kv] = ld8(qb + kv * 16 + g * 8);

    int c0 = w * 128 + l;
    int rr0 = c0 >> 3, sl0 = c0 & 7;
    int kc0 = sl0 ^ (rr0 & 7);
    int rr1 = rr0 + 8, kc1 = sl0 ^ (rr1 & 7);
    const uint16_t* kp0 = kbase + rr0 * 64 + kc0 * 8;
    const uint16_t* kp1 = kbase + rr1 * 64 + kc1 * 8;
    const uint16_t* vp0 = vbase + (size_t)rr0 * 2048 + kc0 * 8;
    const uint16_t* vp1 = vbase + (size_t)rr1 * 2048 + kc1 * 8;
    uint16_t* kd0 = k_lds[0] + w * 1024;
    uint16_t* kd1 = k_lds[1] + w * 1024;
    uint16_t* vd0 = v_lds[0] + w * 1024;
    uint16_t* vd1 = v_lds[1] + w * 1024;

    f32x16 oa[2] = {};
    float lsum = 0.f;

    auto stage = [&](uint16_t* kd, uint16_t* vd) {
        gload16(kp0, kd);       gload16(kp1, kd + 512);   // K first,
        gload16(vp0, vd);       gload16(vp1, vd + 512);   // V second (vmcnt order)
        kp0 += 4096; kp1 += 4096; vp0 += 64; vp1 += 64;
    };

    stage(kd0, vd0);   // tile 0 -> buf 0  (4 outstanding)

    auto body = [&](int t, const uint16_t* kb, const uint16_t* vb,
                    uint16_t* kdn, uint16_t* vdn) {
        asm volatile("s_waitcnt vmcnt(2)\n\ts_barrier" ::: "memory");
        if (t < 31) stage(kdn, vdn);

        bf16x8 pfrag[4];
#pragma unroll
        for (int j = 0; j < 2; ++j) {
            int key = j * 32 + l31;
            f32x16 stj = {};
            __builtin_amdgcn_s_setprio(1);
#pragma unroll
            for (int kv = 0; kv < 4; ++kv) {
                bf16x8 kf = ld8(kb + key * 64 + ((2 * kv + g) ^ (key & 7)) * 8);
                stj = __builtin_amdgcn_mfma_f32_32x32x16_bf16(kf, qf[kv], stj, 0, 0, 0);
            }
            __builtin_amdgcn_s_setprio(0);
#pragma unroll
            for (int h = 0; h < 2; ++h) {
                float e[8];
#pragma unroll
                for (int jj = 0; jj < 8; ++jj) e[jj] = exp2_fast(stj[h * 8 + jj]);
                lsum += ((e[0] + e[1]) + (e[2] + e[3])) + ((e[4] + e[5]) + (e[6] + e[7]));
                uint32_t a0 = cvtpk(e[0], e[1]), a1 = cvtpk(e[2], e[3]);
                uint32_t b0 = cvtpk(e[4], e[5]), b1 = cvtpk(e[6], e[7]);
                auto r0 = __builtin_amdgcn_permlane32_swap(a0, b0, false, false);
                auto r1 = __builtin_amdgcn_permlane32_swap(a1, b1, false, false);
                u32x4 f;
                f[0] = r0[0]; f[1] = r1[0]; f[2] = r0[1]; f[3] = r1[1];
                pfrag[j * 2 + h] = __builtin_bit_cast(bf16x8, f);
            }
        }

        if (t < 31) asm volatile("s_waitcnt vmcnt(4)\n\ts_barrier" ::: "memory");
        else        asm volatile("s_waitcnt vmcnt(0)\n\ts_barrier" ::: "memory");

        __builtin_amdgcn_s_setprio(1);
#pragma unroll
        for (int kv = 0; kv < 4; ++kv) {
#pragma unroll
            for (int dt = 0; dt < 2; ++dt) {
                int dh = dt * 32 + l31;
                bf16x8 vf = ld8(vb + dh * 64 + ((2 * kv + g) ^ (dh & 7)) * 8);
                oa[dt] = __builtin_amdgcn_mfma_f32_32x32x16_bf16(vf, pfrag[kv], oa[dt], 0, 0, 0);
            }
        }
        __builtin_amdgcn_s_setprio(0);
    };

    for (int kt = 0; kt < 32; kt += 2) {
        body(kt,     k_lds[0], v_lds[0], kd1, vd1);
        body(kt + 1, k_lds[1], v_lds[1], kd0, vd0);
    }

    float ltot = lsum + __shfl_xor(lsum, 32, 64);
    float inv = 1.0f / ltot;
    int b = bh >> 4, h = bh & 15;
    uint16_t* ob = o + ((size_t)(b * 2048 + qrow)) * 1024 + h * 64;
#pragma unroll
    for (int dt = 0; dt < 2; ++dt)
#pragma unroll
        for (int rq = 0; rq < 4; ++rq) {
            union { uint16_t u[4]; uint2 v; } pk;
#pragma unroll
            for (int rr = 0; rr < 4; ++rr) pk.u[rr] = f2bf(oa[dt][rq * 4 + rr] * inv);
            int dh0 = dt * 32 + rq * 8 + g * 4;
            *(uint2*)(ob + dh0) = pk.v;
        }
}

extern "C" void kernel_launch(void* const* d_in, const int* in_sizes, int n_in,
                              void* d_out, int out_size, void* d_ws, size_t ws_size,
                              hipStream_t stream) {
    const float* x     = (const float*)d_in[0];
    // d_in[1] = xpos : unused by the reference
    const float* Wqkv  = (const float*)d_in[2];
    const float* Wproj = (const float*)d_in[3];
    const float* bproj = (const float*)d_in[4];
    float* out = (float*)d_out;

    char* ws = (char*)d_ws;
    uint16_t* xb     = (uint16_t*)(ws);                         // 16.78 MB
    uint16_t* wqkvT  = (uint16_t*)(ws + 16777216);              //  6.29 MB
    uint16_t* wprojT = (uint16_t*)(ws + 23068672);              //  2.10 MB
    uint16_t* qws    = (uint16_t*)(ws + 25165824);              // 16.78 MB
    uint16_t* kws    = (uint16_t*)(ws + 41943040);              // 16.78 MB
    uint16_t* vT     = (uint16_t*)(ws + 58720256);              // 16.78 MB (total ~75.5 MB)
    uint16_t* attnout = xb;  // xb is dead after QKV GEMM

    k_prep<<<dim3(5120), dim3(256), 0, stream>>>(x, xb, Wqkv, wqkvT, Wproj, wprojT);
    k_gemm<0><<<dim3(768), dim3(512), 98304, stream>>>(xb, wqkvT, nullptr, qws, kws, vT, nullptr);
    k_attn<<<dim3(1024), dim3(256), 0, stream>>>(qws, kws, vT, attnout);
    k_gemm<1><<<dim3(256), dim3(512), 98304, stream>>>(attnout, wprojT, bproj, nullptr, nullptr, nullptr, out);
}

// Round 17
// 194.447 us; speedup vs baseline: 1.0846x; 1.0077x over previous
//
#include <hip/hip_runtime.h>
#include <stdint.h>

#define DEVINL __device__ __forceinline__

typedef __bf16 bf16x8 __attribute__((ext_vector_type(8)));
typedef float f32x4 __attribute__((ext_vector_type(4)));
typedef float f32x16 __attribute__((ext_vector_type(16)));
typedef uint32_t u32x4 __attribute__((ext_vector_type(4)));

DEVINL uint16_t f2bf(float f) {
    uint32_t u = __builtin_bit_cast(uint32_t, f);
    uint32_t r = (u + 0x7FFFu + ((u >> 16) & 1u)) >> 16;
    return (uint16_t)r;
}

DEVINL bf16x8 ld8(const uint16_t* p) {
    u32x4 v = *(const u32x4*)p;
    return __builtin_bit_cast(bf16x8, v);
}

DEVINL void gload16(const void* g, void* l) {
    __builtin_amdgcn_global_load_lds(
        (const __attribute__((address_space(1))) uint32_t*)g,
        (__attribute__((address_space(3))) uint32_t*)l, 16, 0, 0);
}

DEVINL uint32_t cvtpk(float lo, float hi) {
    uint32_t r;
    asm("v_cvt_pk_bf16_f32 %0, %1, %2" : "=v"(r) : "v"(lo), "v"(hi));
    return r;
}

DEVINL float exp2_fast(float x) {
    float r;
    asm("v_exp_f32 %0, %1" : "=v"(r) : "v"(x));
    return r;
}

// ---------------- fused prep: cvt x -> bf16 ; transpose+cvt Wqkv, Wproj ----------------
DEVINL void transW_body(const float* __restrict__ W, uint16_t* __restrict__ WT,
                        int Nn, int n0, int k0, int tid, uint16_t* t) {
#pragma unroll
    for (int i = 0; i < 4; ++i) {
        int c = tid + i * 256;              // 1024 float4 chunks
        int kr = c >> 4, nc = c & 15;
        float4 v = *(const float4*)(W + (size_t)(k0 + kr) * Nn + n0 + nc * 4);
        t[(nc * 4 + 0) * 65 + kr] = f2bf(v.x);
        t[(nc * 4 + 1) * 65 + kr] = f2bf(v.y);
        t[(nc * 4 + 2) * 65 + kr] = f2bf(v.z);
        t[(nc * 4 + 3) * 65 + kr] = f2bf(v.w);
    }
    __syncthreads();
#pragma unroll
    for (int i = 0; i < 2; ++i) {
        int c = tid + i * 256;              // 512 chunks of 8 bf16
        int nr = c >> 3, kc = c & 7;
        union { uint16_t u[8]; u32x4 v; } o;
#pragma unroll
        for (int j = 0; j < 8; ++j) o.u[j] = t[nr * 65 + kc * 8 + j];
        *(u32x4*)(WT + (size_t)(n0 + nr) * 1024 + k0 + kc * 8) = o.v;
    }
}

__global__ void k_prep(const float* __restrict__ x, uint16_t* __restrict__ xb,
                       const float* __restrict__ Wqkv, uint16_t* __restrict__ wqkvT,
                       const float* __restrict__ Wproj, uint16_t* __restrict__ wprojT) {
    __shared__ uint16_t t[64 * 65];
    int bid = blockIdx.x;
    int tid = threadIdx.x;
    if (bid < 4096) {
        int i = bid * 256 + tid;            // 1048576 chunks of 8 floats
        const float4* src = (const float4*)x + (size_t)i * 2;
        float4 a = src[0], b = src[1];
        union { uint16_t u[8]; u32x4 v; } o;
        o.u[0] = f2bf(a.x); o.u[1] = f2bf(a.y); o.u[2] = f2bf(a.z); o.u[3] = f2bf(a.w);
        o.u[4] = f2bf(b.x); o.u[5] = f2bf(b.y); o.u[6] = f2bf(b.z); o.u[7] = f2bf(b.w);
        ((u32x4*)xb)[i] = o.v;
    } else if (bid < 4864) {
        int idx = bid - 4096;               // 48 x 16 tiles
        transW_body(Wqkv, wqkvT, 3072, (idx % 48) * 64, (idx / 48) * 64, tid, t);
    } else {
        int idx = bid - 4864;               // 16 x 16 tiles
        transW_body(Wproj, wprojT, 1024, (idx % 16) * 64, (idx / 16) * 64, tid, t);
    }
}

// ---------------- GEMM: [8192][1024] x BT[Nd][1024], BM=256 BN=128 BK=64 ----------------
// 8 waves (512 thr), double-buffered dynamic LDS 96KB. Stagger-by-one
// pipeline with ONE order-invariant vmcnt(0)+barrier per K-step.
// R17: stage/compute sub-phase interleave — stageA(s+1) -> MFMA(kk=0) ->
// stageB(s+1) -> MFMA(kk=1) -> drain. Same sync contract as R16 (all of
// s+1's loads issue before the end-of-step vmcnt(0)); only the issue SPREAD
// changes so the memory pipe works under both MFMA sub-phases.
// MODE 0: QKV. nt 0..7 q (scaled), 8..15 k, 16..23 v (LDS-transposed to v^T).
// MODE 1: proj -> out f32 + bias.
template <int MODE>
__global__ __launch_bounds__(512) void k_gemm(
    const uint16_t* __restrict__ A, const uint16_t* __restrict__ BT,
    const float* __restrict__ bias,
    uint16_t* __restrict__ qo, uint16_t* __restrict__ ko, uint16_t* __restrict__ vo,
    float* __restrict__ out) {
    extern __shared__ uint16_t lds[];
    int tid = threadIdx.x;
    int w = tid >> 6, l = tid & 63;
    int l15 = l & 15, l4 = l >> 4;
    int wr = w >> 2, wc = w & 3;
    int bid = blockIdx.x;
    int mt = (bid & 7) * 4 + ((bid >> 3) & 3);   // XCD-chunked M
    int nt = bid >> 5;                            // B-panel index
    int m0 = mt * 256, n0 = nt * 128;

    // staging source pointers: thread covers row r0 (+64*q), swizzled chunk kc
    int r0 = tid >> 3, sl0 = tid & 7;
    int kc = sl0 ^ (r0 & 7);
    const uint16_t* pA = A + (size_t)(m0 + r0) * 1024 + kc * 8;
    const uint16_t* pB = BT + (size_t)(n0 + r0) * 1024 + kc * 8;
    int wofs = w * 512;

    f32x4 acc[8][2] = {};

    auto stageA = [&](int ks, int abA) {
#pragma unroll
        for (int q = 0; q < 4; ++q)          // A: 4 x 64-row groups
            gload16(pA + q * 65536 + ks * 64, lds + abA + q * 4096 + wofs);
    };
    auto stageB = [&](int ks, int abB) {
#pragma unroll
        for (int li = 0; li < 2; ++li)       // B: 2 x 64-row groups
            gload16(pB + li * 65536 + ks * 64, lds + abB + li * 4096 + wofs);
    };

    auto computeHalf = [&](int abA, int abB, int kk) {
        const uint16_t* Ah = lds + abA + wr * 8192;
        const uint16_t* Bb = lds + abB;
        int ch = ((kk * 4 + l4) ^ (l15 & 7)) * 8;
        bf16x8 af[8], bf[2];
#pragma unroll
        for (int fi = 0; fi < 8; ++fi)
            af[fi] = ld8(Ah + (fi * 16 + l15) * 64 + ch);
#pragma unroll
        for (int fj = 0; fj < 2; ++fj)
            bf[fj] = ld8(Bb + (wc * 32 + fj * 16 + l15) * 64 + ch);
        __builtin_amdgcn_s_setprio(1);
#pragma unroll
        for (int fi = 0; fi < 8; ++fi)
#pragma unroll
            for (int fj = 0; fj < 2; ++fj)
                acc[fi][fj] = __builtin_amdgcn_mfma_f32_16x16x32_bf16(
                    af[fi], bf[fj], acc[fi][fj], 0, 0, 0);
        __builtin_amdgcn_s_setprio(0);
    };

    // step body: stage s+1 split around compute-s's two halves; one drain/step
    auto step = [&](int s, int abA, int abB, int abAn, int abBn) {
        bool pf = (s + 1 < 16);
        if (pf) stageA(s + 1, abAn);
        computeHalf(abA, abB, 0);
        if (pf) stageB(s + 1, abBn);
        computeHalf(abA, abB, 1);
        asm volatile("s_waitcnt vmcnt(0)\n\ts_barrier" ::: "memory");
    };

    stageA(0, 0); stageB(0, 32768);
    asm volatile("s_waitcnt vmcnt(0)\n\ts_barrier" ::: "memory");
    for (int s = 0; s < 16; s += 2) {
        step(s,     0,     32768, 16384, 40960);
        step(s + 1, 16384, 40960, 0,     32768);
    }

    if constexpr (MODE == 0) {
        int b = m0 >> 11, nbase = m0 & 2047;
        if (n0 >= 2048) {
            // ---- v-block: transpose 256x128 acc tile in LDS -> v^T [bh][dh][n] ----
            // lds as [128 d][264] (row stride 264 elems keeps 16B alignment)
#pragma unroll
            for (int fi = 0; fi < 8; ++fi)
#pragma unroll
                for (int fj = 0; fj < 2; ++fj) {
                    int dl = wc * 32 + fj * 16 + l15;
                    int ml = wr * 128 + fi * 16 + l4 * 4;
                    union { uint16_t u[4]; uint2 v2; } pk;
#pragma unroll
                    for (int r = 0; r < 4; ++r) pk.u[r] = f2bf(acc[fi][fj][r]);
                    *(uint2*)&lds[dl * 264 + ml] = pk.v2;
                }
        __syncthreads();
#pragma unroll
            for (int it = 0; it < 8; ++it) {
                int idx = it * 512 + tid;
                int row = idx >> 5, col = (idx & 31) * 8;   // 128 x 256 in 16B chunks
                u32x4 val = *(u32x4*)&lds[row * 264 + col];
                int dv = (n0 - 2048) + row;
                int h = dv >> 6, dh = dv & 63;
                *(u32x4*)(vo + ((size_t)(b * 16 + h) * 64 + dh) * 2048 + nbase + col) = val;
            }
        } else {
            float sc = (n0 < 1024) ? 0.18033688011112042f : 1.0f;  // q exp2-domain prescale
            uint16_t* dst0 = (n0 < 1024) ? qo : ko;
#pragma unroll
            for (int fi = 0; fi < 8; ++fi)
#pragma unroll
                for (int fj = 0; fj < 2; ++fj) {
                    int d = n0 + wc * 32 + fj * 16 + l15;
                    int h = (d >> 6) & 15, dh = d & 63;
#pragma unroll
                    for (int r = 0; r < 4; ++r) {
                        int n = nbase + wr * 128 + fi * 16 + l4 * 4 + r;
                        dst0[((size_t)(b * 16 + h) * 2048 + n) * 64 + dh] = f2bf(acc[fi][fj][r] * sc);
                    }
                }
        }
    } else {
#pragma unroll
        for (int fj = 0; fj < 2; ++fj) {
            int d = n0 + wc * 32 + fj * 16 + l15;
            float bv = bias[d];
#pragma unroll
            for (int fi = 0; fi < 8; ++fi)
#pragma unroll
                for (int r = 0; r < 4; ++r) {
                    int m = m0 + wr * 128 + fi * 16 + l4 * 4 + r;
                    out[(size_t)m * 1024 + d] = acc[fi][fj][r] + bv;
                }
        }
    }
}

// ---------------- flash attention (no-max softmax, exp2 domain) ----------------
// R12-proven body EXACT (103.5 us, VGPR 84): 4-wave blocks, split-barrier
// counted-vmcnt pipeline, K/V in LDS, scalar lsum, XCD swizzle. FROZEN.
// (Issue-port-bound: R9's barrier-free variant measured 92% combined
// VALU+MFMA busy at the same 104us; 7 structural variants within +-3%.)
__global__ __launch_bounds__(256) void k_attn(
    const uint16_t* __restrict__ q, const uint16_t* __restrict__ kk_,
    const uint16_t* __restrict__ vt, uint16_t* __restrict__ o) {
    __shared__ uint16_t k_lds[2][64 * 64];
    __shared__ uint16_t v_lds[2][64 * 64];
    int tid = threadIdx.x;
    int w = tid >> 6, l = tid & 63;
    int l31 = l & 31, g = l >> 5;
    int bid = blockIdx.x;
    int slot = bid >> 3;
    int bh = (bid & 7) * 8 + (slot >> 4);
    int qt = slot & 15;
    int qrow = qt * 128 + w * 32 + l31;
    const uint16_t* qb = q + ((size_t)bh * 2048 + qrow) * 64;
    const uint16_t* kbase = kk_ + (size_t)bh * 2048 * 64;
    const uint16_t* vbase = vt + (size_t)bh * 64 * 2048;

    bf16x8 qf[4];
#pragma unroll
    for (int kv = 0; kv < 4; ++kv) qf[kv] = ld8(qb + kv * 16 + g * 8);

    int c0 = w * 128 + l;
    int rr0 = c0 >> 3, sl0 = c0 & 7;
    int kc0 = sl0 ^ (rr0 & 7);
    int rr1 = rr0 + 8, kc1 = sl0 ^ (rr1 & 7);
    const uint16_t* kp0 = kbase + rr0 * 64 + kc0 * 8;
    const uint16_t* kp1 = kbase + rr1 * 64 + kc1 * 8;
    const uint16_t* vp0 = vbase + (size_t)rr0 * 2048 + kc0 * 8;
    const uint16_t* vp1 = vbase + (size_t)rr1 * 2048 + kc1 * 8;
    uint16_t* kd0 = k_lds[0] + w * 1024;
    uint16_t* kd1 = k_lds[1] + w * 1024;
    uint16_t* vd0 = v_lds[0] + w * 1024;
    uint16_t* vd1 = v_lds[1] + w * 1024;

    f32x16 oa[2] = {};
    float lsum = 0.f;

    auto stage = [&](uint16_t* kd, uint16_t* vd) {
        gload16(kp0, kd);       gload16(kp1, kd + 512);   // K first,
        gload16(vp0, vd);       gload16(vp1, vd + 512);   // V second (vmcnt order)
        kp0 += 4096; kp1 += 4096; vp0 += 64; vp1 += 64;
    };

    stage(kd0, vd0);   // tile 0 -> buf 0  (4 outstanding)

    auto body = [&](int t, const uint16_t* kb, const uint16_t* vb,
                    uint16_t* kdn, uint16_t* vdn) {
        asm volatile("s_waitcnt vmcnt(2)\n\ts_barrier" ::: "memory");
        if (t < 31) stage(kdn, vdn);

        bf16x8 pfrag[4];
#pragma unroll
        for (int j = 0; j < 2; ++j) {
            int key = j * 32 + l31;
            f32x16 stj = {};
            __builtin_amdgcn_s_setprio(1);
#pragma unroll
            for (int kv = 0; kv < 4; ++kv) {
                bf16x8 kf = ld8(kb + key * 64 + ((2 * kv + g) ^ (key & 7)) * 8);
                stj = __builtin_amdgcn_mfma_f32_32x32x16_bf16(kf, qf[kv], stj, 0, 0, 0);
            }
            __builtin_amdgcn_s_setprio(0);
#pragma unroll
            for (int h = 0; h < 2; ++h) {
                float e[8];
#pragma unroll
                for (int jj = 0; jj < 8; ++jj) e[jj] = exp2_fast(stj[h * 8 + jj]);
                lsum += ((e[0] + e[1]) + (e[2] + e[3])) + ((e[4] + e[5]) + (e[6] + e[7]));
                uint32_t a0 = cvtpk(e[0], e[1]), a1 = cvtpk(e[2], e[3]);
                uint32_t b0 = cvtpk(e[4], e[5]), b1 = cvtpk(e[6], e[7]);
                auto r0 = __builtin_amdgcn_permlane32_swap(a0, b0, false, false);
                auto r1 = __builtin_amdgcn_permlane32_swap(a1, b1, false, false);
                u32x4 f;
                f[0] = r0[0]; f[1] = r1[0]; f[2] = r0[1]; f[3] = r1[1];
                pfrag[j * 2 + h] = __builtin_bit_cast(bf16x8, f);
            }
        }

        if (t < 31) asm volatile("s_waitcnt vmcnt(4)\n\ts_barrier" ::: "memory");
        else        asm volatile("s_waitcnt vmcnt(0)\n\ts_barrier" ::: "memory");

        __builtin_amdgcn_s_setprio(1);
#pragma unroll
        for (int kv = 0; kv < 4; ++kv) {
#pragma unroll
            for (int dt = 0; dt < 2; ++dt) {
                int dh = dt * 32 + l31;
                bf16x8 vf = ld8(vb + dh * 64 + ((2 * kv + g) ^ (dh & 7)) * 8);
                oa[dt] = __builtin_amdgcn_mfma_f32_32x32x16_bf16(vf, pfrag[kv], oa[dt], 0, 0, 0);
            }
        }
        __builtin_amdgcn_s_setprio(0);
    };

    for (int kt = 0; kt < 32; kt += 2) {
        body(kt,     k_lds[0], v_lds[0], kd1, vd1);
        body(kt + 1, k_lds[1], v_lds[1], kd0, vd0);
    }

    float ltot = lsum + __shfl_xor(lsum, 32, 64);
    float inv = 1.0f / ltot;
    int b = bh >> 4, h = bh & 15;
    uint16_t* ob = o + ((size_t)(b * 2048 + qrow)) * 1024 + h * 64;
#pragma unroll
    for (int dt = 0; dt < 2; ++dt)
#pragma unroll
        for (int rq = 0; rq < 4; ++rq) {
            union { uint16_t u[4]; uint2 v; } pk;
#pragma unroll
            for (int rr = 0; rr < 4; ++rr) pk.u[rr] = f2bf(oa[dt][rq * 4 + rr] * inv);
            int dh0 = dt * 32 + rq * 8 + g * 4;
            *(uint2*)(ob + dh0) = pk.v;
        }
}

extern "C" void kernel_launch(void* const* d_in, const int* in_sizes, int n_in,
                              void* d_out, int out_size, void* d_ws, size_t ws_size,
                              hipStream_t stream) {
    const float* x     = (const float*)d_in[0];
    // d_in[1] = xpos : unused by the reference
    const float* Wqkv  = (const float*)d_in[2];
    const float* Wproj = (const float*)d_in[3];
    const float* bproj = (const float*)d_in[4];
    float* out = (float*)d_out;

    char* ws = (char*)d_ws;
    uint16_t* xb     = (uint16_t*)(ws);                         // 16.78 MB
    uint16_t* wqkvT  = (uint16_t*)(ws + 16777216);              //  6.29 MB
    uint16_t* wprojT = (uint16_t*)(ws + 23068672);              //  2.10 MB
    uint16_t* qws    = (uint16_t*)(ws + 25165824);              // 16.78 MB
    uint16_t* kws    = (uint16_t*)(ws + 41943040);              // 16.78 MB
    uint16_t* vT     = (uint16_t*)(ws + 58720256);              // 16.78 MB (total ~75.5 MB)
    uint16_t* attnout = xb;  // xb is dead after QKV GEMM

    k_prep<<<dim3(5120), dim3(256), 0, stream>>>(x, xb, Wqkv, wqkvT, Wproj, wprojT);
    k_gemm<0><<<dim3(768), dim3(512), 98304, stream>>>(xb, wqkvT, nullptr, qws, kws, vT, nullptr);
    k_attn<<<dim3(1024), dim3(256), 0, stream>>>(qws, kws, vT, attnout);
    k_gemm<1><<<dim3(256), dim3(512), 98304, stream>>>(attnout, wprojT, bproj, nullptr, nullptr, nullptr, out);
}

// Round 18
// 189.126 us; speedup vs baseline: 1.1151x; 1.0281x over previous
//
#include <hip/hip_runtime.h>
#include <stdint.h>

#define DEVINL __device__ __forceinline__

typedef __bf16 bf16x8 __attribute__((ext_vector_type(8)));
typedef float f32x4 __attribute__((ext_vector_type(4)));
typedef float f32x16 __attribute__((ext_vector_type(16)));
typedef uint32_t u32x4 __attribute__((ext_vector_type(4)));

DEVINL uint16_t f2bf(float f) {
    uint32_t u = __builtin_bit_cast(uint32_t, f);
    uint32_t r = (u + 0x7FFFu + ((u >> 16) & 1u)) >> 16;
    return (uint16_t)r;
}

DEVINL bf16x8 ld8(const uint16_t* p) {
    u32x4 v = *(const u32x4*)p;
    return __builtin_bit_cast(bf16x8, v);
}

DEVINL void gload16(const void* g, void* l) {
    __builtin_amdgcn_global_load_lds(
        (const __attribute__((address_space(1))) uint32_t*)g,
        (__attribute__((address_space(3))) uint32_t*)l, 16, 0, 0);
}

DEVINL uint32_t cvtpk(float lo, float hi) {
    uint32_t r;
    asm("v_cvt_pk_bf16_f32 %0, %1, %2" : "=v"(r) : "v"(lo), "v"(hi));
    return r;
}

DEVINL float exp2_fast(float x) {
    float r;
    asm("v_exp_f32 %0, %1" : "=v"(r) : "v"(x));
    return r;
}

// ---------------- fused prep: cvt x -> bf16 ; transpose+cvt Wqkv, Wproj ----------------
DEVINL void transW_body(const float* __restrict__ W, uint16_t* __restrict__ WT,
                        int Nn, int n0, int k0, int tid, uint16_t* t) {
#pragma unroll
    for (int i = 0; i < 4; ++i) {
        int c = tid + i * 256;              // 1024 float4 chunks
        int kr = c >> 4, nc = c & 15;
        float4 v = *(const float4*)(W + (size_t)(k0 + kr) * Nn + n0 + nc * 4);
        t[(nc * 4 + 0) * 65 + kr] = f2bf(v.x);
        t[(nc * 4 + 1) * 65 + kr] = f2bf(v.y);
        t[(nc * 4 + 2) * 65 + kr] = f2bf(v.z);
        t[(nc * 4 + 3) * 65 + kr] = f2bf(v.w);
    }
    __syncthreads();
#pragma unroll
    for (int i = 0; i < 2; ++i) {
        int c = tid + i * 256;              // 512 chunks of 8 bf16
        int nr = c >> 3, kc = c & 7;
        union { uint16_t u[8]; u32x4 v; } o;
#pragma unroll
        for (int j = 0; j < 8; ++j) o.u[j] = t[nr * 65 + kc * 8 + j];
        *(u32x4*)(WT + (size_t)(n0 + nr) * 1024 + k0 + kc * 8) = o.v;
    }
}

__global__ void k_prep(const float* __restrict__ x, uint16_t* __restrict__ xb,
                       const float* __restrict__ Wqkv, uint16_t* __restrict__ wqkvT,
                       const float* __restrict__ Wproj, uint16_t* __restrict__ wprojT) {
    __shared__ uint16_t t[64 * 65];
    int bid = blockIdx.x;
    int tid = threadIdx.x;
    if (bid < 4096) {
        int i = bid * 256 + tid;            // 1048576 chunks of 8 floats
        const float4* src = (const float4*)x + (size_t)i * 2;
        float4 a = src[0], b = src[1];
        union { uint16_t u[8]; u32x4 v; } o;
        o.u[0] = f2bf(a.x); o.u[1] = f2bf(a.y); o.u[2] = f2bf(a.z); o.u[3] = f2bf(a.w);
        o.u[4] = f2bf(b.x); o.u[5] = f2bf(b.y); o.u[6] = f2bf(b.z); o.u[7] = f2bf(b.w);
        ((u32x4*)xb)[i] = o.v;
    } else if (bid < 4864) {
        int idx = bid - 4096;               // 48 x 16 tiles
        transW_body(Wqkv, wqkvT, 3072, (idx % 48) * 64, (idx / 48) * 64, tid, t);
    } else {
        int idx = bid - 4864;               // 16 x 16 tiles
        transW_body(Wproj, wprojT, 1024, (idx % 16) * 64, (idx / 16) * 64, tid, t);
    }
}

// ---------------- GEMM: [8192][1024] x BT[Nd][1024], BM=256 BN=128 BK=64 ----------------
// 8 waves (512 thr), double-buffered dynamic LDS 96KB. Stagger-by-one
// pipeline with ONE order-invariant vmcnt(0)+barrier per K-step; stage/compute
// sub-phase interleave (R17, +1.5us).
// MODE 0: QKV. nt 0..7 q (scaled), 8..15 k, 16..23 v (LDS-transposed to v^T).
// MODE 1: proj -> out f32 + bias.
template <int MODE>
__global__ __launch_bounds__(512) void k_gemm(
    const uint16_t* __restrict__ A, const uint16_t* __restrict__ BT,
    const float* __restrict__ bias,
    uint16_t* __restrict__ qo, uint16_t* __restrict__ ko, uint16_t* __restrict__ vo,
    float* __restrict__ out) {
    extern __shared__ uint16_t lds[];
    int tid = threadIdx.x;
    int w = tid >> 6, l = tid & 63;
    int l15 = l & 15, l4 = l >> 4;
    int wr = w >> 2, wc = w & 3;
    int bid = blockIdx.x;
    int mt = (bid & 7) * 4 + ((bid >> 3) & 3);   // XCD-chunked M
    int nt = bid >> 5;                            // B-panel index
    int m0 = mt * 256, n0 = nt * 128;

    int r0 = tid >> 3, sl0 = tid & 7;
    int kc = sl0 ^ (r0 & 7);
    const uint16_t* pA = A + (size_t)(m0 + r0) * 1024 + kc * 8;
    const uint16_t* pB = BT + (size_t)(n0 + r0) * 1024 + kc * 8;
    int wofs = w * 512;

    f32x4 acc[8][2] = {};

    auto stageA = [&](int ks, int abA) {
#pragma unroll
        for (int q = 0; q < 4; ++q)
            gload16(pA + q * 65536 + ks * 64, lds + abA + q * 4096 + wofs);
    };
    auto stageB = [&](int ks, int abB) {
#pragma unroll
        for (int li = 0; li < 2; ++li)
            gload16(pB + li * 65536 + ks * 64, lds + abB + li * 4096 + wofs);
    };

    auto computeHalf = [&](int abA, int abB, int kk) {
        const uint16_t* Ah = lds + abA + wr * 8192;
        const uint16_t* Bb = lds + abB;
        int ch = ((kk * 4 + l4) ^ (l15 & 7)) * 8;
        bf16x8 af[8], bf[2];
#pragma unroll
        for (int fi = 0; fi < 8; ++fi)
            af[fi] = ld8(Ah + (fi * 16 + l15) * 64 + ch);
#pragma unroll
        for (int fj = 0; fj < 2; ++fj)
            bf[fj] = ld8(Bb + (wc * 32 + fj * 16 + l15) * 64 + ch);
        __builtin_amdgcn_s_setprio(1);
#pragma unroll
        for (int fi = 0; fi < 8; ++fi)
#pragma unroll
            for (int fj = 0; fj < 2; ++fj)
                acc[fi][fj] = __builtin_amdgcn_mfma_f32_16x16x32_bf16(
                    af[fi], bf[fj], acc[fi][fj], 0, 0, 0);
        __builtin_amdgcn_s_setprio(0);
    };

    auto step = [&](int s, int abA, int abB, int abAn, int abBn) {
        bool pf = (s + 1 < 16);
        if (pf) stageA(s + 1, abAn);
        computeHalf(abA, abB, 0);
        if (pf) stageB(s + 1, abBn);
        computeHalf(abA, abB, 1);
        asm volatile("s_waitcnt vmcnt(0)\n\ts_barrier" ::: "memory");
    };

    stageA(0, 0); stageB(0, 32768);
    asm volatile("s_waitcnt vmcnt(0)\n\ts_barrier" ::: "memory");
    for (int s = 0; s < 16; s += 2) {
        step(s,     0,     32768, 16384, 40960);
        step(s + 1, 16384, 40960, 0,     32768);
    }

    if constexpr (MODE == 0) {
        int b = m0 >> 11, nbase = m0 & 2047;
        if (n0 >= 2048) {
#pragma unroll
            for (int fi = 0; fi < 8; ++fi)
#pragma unroll
                for (int fj = 0; fj < 2; ++fj) {
                    int dl = wc * 32 + fj * 16 + l15;
                    int ml = wr * 128 + fi * 16 + l4 * 4;
                    union { uint16_t u[4]; uint2 v2; } pk;
#pragma unroll
                    for (int r = 0; r < 4; ++r) pk.u[r] = f2bf(acc[fi][fj][r]);
                    *(uint2*)&lds[dl * 264 + ml] = pk.v2;
                }
        __syncthreads();
#pragma unroll
            for (int it = 0; it < 8; ++it) {
                int idx = it * 512 + tid;
                int row = idx >> 5, col = (idx & 31) * 8;
                u32x4 val = *(u32x4*)&lds[row * 264 + col];
                int dv = (n0 - 2048) + row;
                int h = dv >> 6, dh = dv & 63;
                *(u32x4*)(vo + ((size_t)(b * 16 + h) * 64 + dh) * 2048 + nbase + col) = val;
            }
        } else {
            float sc = (n0 < 1024) ? 0.18033688011112042f : 1.0f;
            uint16_t* dst0 = (n0 < 1024) ? qo : ko;
#pragma unroll
            for (int fi = 0; fi < 8; ++fi)
#pragma unroll
                for (int fj = 0; fj < 2; ++fj) {
                    int d = n0 + wc * 32 + fj * 16 + l15;
                    int h = (d >> 6) & 15, dh = d & 63;
#pragma unroll
                    for (int r = 0; r < 4; ++r) {
                        int n = nbase + wr * 128 + fi * 16 + l4 * 4 + r;
                        dst0[((size_t)(b * 16 + h) * 2048 + n) * 64 + dh] = f2bf(acc[fi][fj][r] * sc);
                    }
                }
        }
    } else {
#pragma unroll
        for (int fj = 0; fj < 2; ++fj) {
            int d = n0 + wc * 32 + fj * 16 + l15;
            float bv = bias[d];
#pragma unroll
            for (int fi = 0; fi < 8; ++fi)
#pragma unroll
                for (int r = 0; r < 4; ++r) {
                    int m = m0 + wr * 128 + fi * 16 + l4 * 4 + r;
                    out[(size_t)m * 1024 + d] = acc[fi][fj][r] + bv;
                }
        }
    }
}

// ---------------- flash attention (no-max softmax, exp2 domain, KVBLK=128) ----------------
// R18: R12's proven 4-wave structure with doubled KV tile (128 keys) — halves
// the wait+barrier pairs (64->32) and amortizes addressing. Same split-barrier
// counted-vmcnt pattern, counts re-derived for 8 loads/stage:
//   body t: vmcnt(4)+bar [K(t) ready; V(t) 4 in flight] -> stage(t+1): 8 loads,
//   K first then V -> QK(4 j-groups)+exp -> vmcnt(8)+bar [V(t) ready; t+1's 8
//   in flight] -> PV (8 kv-slots). Tail t=15: vmcnt(0).
// LDS: K[2][128][64] + V^T[2][64][128] = 64KB. pfrag[8] (+16 VGPR, stays <128).
__global__ __launch_bounds__(256) void k_attn(
    const uint16_t* __restrict__ q, const uint16_t* __restrict__ kk_,
    const uint16_t* __restrict__ vt, uint16_t* __restrict__ o) {
    __shared__ uint16_t k_lds[2][128 * 64];
    __shared__ uint16_t v_lds[2][64 * 128];
    int tid = threadIdx.x;
    int w = tid >> 6, l = tid & 63;
    int l31 = l & 31, g = l >> 5;
    int bid = blockIdx.x;
    int slot = bid >> 3;
    int bh = (bid & 7) * 8 + (slot >> 4);
    int qt = slot & 15;
    int qrow = qt * 128 + w * 32 + l31;
    const uint16_t* qb = q + ((size_t)bh * 2048 + qrow) * 64;
    const uint16_t* kbase = kk_ + (size_t)bh * 2048 * 64;
    const uint16_t* vbase = vt + (size_t)bh * 64 * 2048;

    bf16x8 qf[4];
#pragma unroll
    for (int kv = 0; kv < 4; ++kv) qf[kv] = ld8(qb + kv * 16 + g * 8);

    // K staging: thread covers chunks c0+{0,64,128,192} (rows rrK+{0,8,16,24},
    // same slot; (rrK+8i)&7 == rrK&7 so one swizzled base + imm offsets works)
    int c0 = w * 256 + l;
    int rrK = c0 >> 3, slK = c0 & 7;
    int kcK = slK ^ (rrK & 7);
    const uint16_t* kp = kbase + (size_t)rrK * 64 + kcK * 8;
    // V^T staging: load i covers row rv0+4i, slot l&15 (XOR low-3 swizzle)
    int rv0 = w * 16 + (l >> 4);
    int sv = l & 15;
    const uint16_t* vpp0 = vbase + (size_t)(rv0 + 0)  * 2048 + (sv ^ ((rv0 + 0)  & 7)) * 8;
    const uint16_t* vpp1 = vbase + (size_t)(rv0 + 4)  * 2048 + (sv ^ ((rv0 + 4)  & 7)) * 8;
    const uint16_t* vpp2 = vbase + (size_t)(rv0 + 8)  * 2048 + (sv ^ ((rv0 + 8)  & 7)) * 8;
    const uint16_t* vpp3 = vbase + (size_t)(rv0 + 12) * 2048 + (sv ^ ((rv0 + 12) & 7)) * 8;
    uint16_t* kd0 = k_lds[0] + w * 2048;
    uint16_t* kd1 = k_lds[1] + w * 2048;
    uint16_t* vd0 = v_lds[0] + w * 2048;
    uint16_t* vd1 = v_lds[1] + w * 2048;

    f32x16 oa[2] = {};
    float lsum = 0.f;

    auto stage = [&](uint16_t* kd, uint16_t* vd) {
        gload16(kp,        kd);        gload16(kp + 512,  kd + 512);   // K first,
        gload16(kp + 1024, kd + 1024); gload16(kp + 1536, kd + 1536);
        gload16(vpp0, vd);        gload16(vpp1, vd + 512);             // V second
        gload16(vpp2, vd + 1024); gload16(vpp3, vd + 1536);
        kp += 8192;
        vpp0 += 128; vpp1 += 128; vpp2 += 128; vpp3 += 128;
    };

    stage(kd0, vd0);   // tile 0 -> buf 0  (8 outstanding)

    auto body = [&](int t, const uint16_t* kb, const uint16_t* vb,
                    uint16_t* kdn, uint16_t* vdn) {
        // K(t) ready for all waves (V(t)'s 4 still in flight)
        asm volatile("s_waitcnt vmcnt(4)\n\ts_barrier" ::: "memory");
        if (t < 15) stage(kdn, vdn);   // issue next tile ASAP

        // S^T = K * Q^T, P = exp2(S) in-register (4 x 32-key groups)
        bf16x8 pfrag[8];
#pragma unroll
        for (int j = 0; j < 4; ++j) {
            int key = j * 32 + l31;
            f32x16 stj = {};
            __builtin_amdgcn_s_setprio(1);
#pragma unroll
            for (int kv = 0; kv < 4; ++kv) {
                bf16x8 kf = ld8(kb + key * 64 + ((2 * kv + g) ^ (key & 7)) * 8);
                stj = __builtin_amdgcn_mfma_f32_32x32x16_bf16(kf, qf[kv], stj, 0, 0, 0);
            }
            __builtin_amdgcn_s_setprio(0);
#pragma unroll
            for (int h = 0; h < 2; ++h) {
                float e[8];
#pragma unroll
                for (int jj = 0; jj < 8; ++jj) e[jj] = exp2_fast(stj[h * 8 + jj]);
                lsum += ((e[0] + e[1]) + (e[2] + e[3])) + ((e[4] + e[5]) + (e[6] + e[7]));
                uint32_t a0 = cvtpk(e[0], e[1]), a1 = cvtpk(e[2], e[3]);
                uint32_t b0 = cvtpk(e[4], e[5]), b1 = cvtpk(e[6], e[7]);
                auto r0 = __builtin_amdgcn_permlane32_swap(a0, b0, false, false);
                auto r1 = __builtin_amdgcn_permlane32_swap(a1, b1, false, false);
                u32x4 f;
                f[0] = r0[0]; f[1] = r1[0]; f[2] = r0[1]; f[3] = r1[1];
                pfrag[j * 2 + h] = __builtin_bit_cast(bf16x8, f);
            }
        }

        // V(t) ready (t+1's 8 loads in flight)
        if (t < 15) asm volatile("s_waitcnt vmcnt(8)\n\ts_barrier" ::: "memory");
        else        asm volatile("s_waitcnt vmcnt(0)\n\ts_barrier" ::: "memory");

        // O^T += V^T * P^T  (8 x 16-key slots)
        __builtin_amdgcn_s_setprio(1);
#pragma unroll
        for (int kv = 0; kv < 8; ++kv) {
#pragma unroll
            for (int dt = 0; dt < 2; ++dt) {
                int dh = dt * 32 + l31;
                bf16x8 vf = ld8(vb + dh * 128 + ((2 * kv + g) ^ (dh & 7)) * 8);
                oa[dt] = __builtin_amdgcn_mfma_f32_32x32x16_bf16(vf, pfrag[kv], oa[dt], 0, 0, 0);
            }
        }
        __builtin_amdgcn_s_setprio(0);
    };

    for (int kt = 0; kt < 16; kt += 2) {
        body(kt,     k_lds[0], v_lds[0], kd1, vd1);
        body(kt + 1, k_lds[1], v_lds[1], kd0, vd0);
    }

    float ltot = lsum + __shfl_xor(lsum, 32, 64);
    float inv = 1.0f / ltot;
    int b = bh >> 4, h = bh & 15;
    uint16_t* ob = o + ((size_t)(b * 2048 + qrow)) * 1024 + h * 64;
#pragma unroll
    for (int dt = 0; dt < 2; ++dt)
#pragma unroll
        for (int rq = 0; rq < 4; ++rq) {
            union { uint16_t u[4]; uint2 v; } pk;
#pragma unroll
            for (int rr = 0; rr < 4; ++rr) pk.u[rr] = f2bf(oa[dt][rq * 4 + rr] * inv);
            int dh0 = dt * 32 + rq * 8 + g * 4;
            *(uint2*)(ob + dh0) = pk.v;
        }
}

extern "C" void kernel_launch(void* const* d_in, const int* in_sizes, int n_in,
                              void* d_out, int out_size, void* d_ws, size_t ws_size,
                              hipStream_t stream) {
    const float* x     = (const float*)d_in[0];
    // d_in[1] = xpos : unused by the reference
    const float* Wqkv  = (const float*)d_in[2];
    const float* Wproj = (const float*)d_in[3];
    const float* bproj = (const float*)d_in[4];
    float* out = (float*)d_out;

    char* ws = (char*)d_ws;
    uint16_t* xb     = (uint16_t*)(ws);                         // 16.78 MB
    uint16_t* wqkvT  = (uint16_t*)(ws + 16777216);              //  6.29 MB
    uint16_t* wprojT = (uint16_t*)(ws + 23068672);              //  2.10 MB
    uint16_t* qws    = (uint16_t*)(ws + 25165824);              // 16.78 MB
    uint16_t* kws    = (uint16_t*)(ws + 41943040);              // 16.78 MB
    uint16_t* vT     = (uint16_t*)(ws + 58720256);              // 16.78 MB (total ~75.5 MB)
    uint16_t* attnout = xb;  // xb is dead after QKV GEMM

    k_prep<<<dim3(5120), dim3(256), 0, stream>>>(x, xb, Wqkv, wqkvT, Wproj, wprojT);
    k_gemm<0><<<dim3(768), dim3(512), 98304, stream>>>(xb, wqkvT, nullptr, qws, kws, vT, nullptr);
    k_attn<<<dim3(1024), dim3(256), 0, stream>>>(qws, kws, vT, attnout);
    k_gemm<1><<<dim3(256), dim3(512), 98304, stream>>>(attnout, wprojT, bproj, nullptr, nullptr, nullptr, out);
}